// Round 10
// baseline (368.018 us; speedup 1.0000x reference)
//
#include <hip/hip_runtime.h>
#include <cstdint>
#include <cstddef>

typedef unsigned short u16;
typedef __attribute__((ext_vector_type(8))) short bf16x8;
typedef __attribute__((ext_vector_type(4))) float f32x4;

#define PB 256     // partition blocks for binA/binC
#define MAXSB 256  // max super-bins (N <= 131072 at 512 rows/bin)
#define SB 512     // rows per super-bin
#define CAP 12288  // LDS perm capacity in binD2
#define DHN 16384  // degree-sort buckets: min(deg,255)<<6 | (r&63)

// ---------------- bf16 helpers (RNE) ----------------
__device__ __forceinline__ float bflo(unsigned u) { return __uint_as_float(u << 16); }
__device__ __forceinline__ float bfhi(unsigned u) { return __uint_as_float(u & 0xFFFF0000u); }
__device__ __forceinline__ u16 f2bf(float f) {
    unsigned u = __float_as_uint(f);
    u += 0x7FFFu + ((u >> 16) & 1u);
    return (u16)(u >> 16);
}
__device__ __forceinline__ unsigned pack2(float a, float b) {
    return (unsigned)f2bf(a) | ((unsigned)f2bf(b) << 16);
}

// ================= CSR build: super-binned, zero global hot atomics =================
// super-bin = 512 rows (row>>9); record = {col | (row&511)<<17, w}

__global__ __launch_bounds__(256) void binA(const int* __restrict__ row, int* __restrict__ P,
                                            int E, int NB, int EB) {
    __shared__ int hist[MAXSB];
    int b = blockIdx.x;
    hist[threadIdx.x] = 0;
    __syncthreads();
    int e0 = b * EB, e1 = min(E, e0 + EB);
    for (int e = e0 + threadIdx.x; e < e1; e += 256)
        atomicAdd(&hist[row[e] >> 9], 1);
    __syncthreads();
    if (threadIdx.x < NB) P[(size_t)threadIdx.x * PB + b] = hist[threadIdx.x];
}

// per-bin exclusive scan over the PB=256 block-partials; emit bin totals
__global__ __launch_bounds__(256) void binB1(int* __restrict__ P, int* __restrict__ bintot) {
    __shared__ int sh[256];
    int* p = P + (size_t)blockIdx.x * PB;
    int tid = threadIdx.x;
    int v = p[tid];
    sh[tid] = v;
    __syncthreads();
    for (int off = 1; off < 256; off <<= 1) {
        int t = (tid >= off) ? sh[tid - off] : 0;
        __syncthreads();
        sh[tid] += t;
        __syncthreads();
    }
    p[tid] = sh[tid] - v;
    if (tid == 255) bintot[blockIdx.x] = sh[255];
}

// helper: inclusive scan of bintot into bs[] (256 entries, in LDS)
__device__ __forceinline__ void bs_scan(int* bs, const int* bintot, int NB, int tid) {
    bs[tid] = (tid < NB) ? bintot[tid] : 0;
    __syncthreads();
    for (int off = 1; off < 256; off <<= 1) {
        int t = (tid >= off) ? bs[tid - off] : 0;
        __syncthreads();
        bs[tid] += t;
        __syncthreads();
    }
}

__global__ __launch_bounds__(256) void binC(const int* __restrict__ row, const int* __restrict__ col,
                                            const float* __restrict__ w, const int* __restrict__ P,
                                            const int* __restrict__ bintot, int2* __restrict__ rec,
                                            int E, int NB, int EB) {
    __shared__ int bs[MAXSB];
    __shared__ int cur[MAXSB];
    int b = blockIdx.x;
    int tid = threadIdx.x;
    bs_scan(bs, bintot, NB, tid);
    if (tid < NB) cur[tid] = (tid ? bs[tid - 1] : 0) + P[(size_t)tid * PB + b];
    __syncthreads();
    int e0 = b * EB, e1 = min(E, e0 + EB);
    for (int e = e0 + tid; e < e1; e += 256) {
        int r = row[e];
        int bin = r >> 9;
        int slot = atomicAdd(&cur[bin], 1);
        rec[slot] = make_int2(col[e] | ((r & 511) << 17), __float_as_int(w[e]));
    }
}

// per-bin counts + deg -> rowp + dinv (wave-level scan, 256 threads)
__global__ __launch_bounds__(256) void binD1(const int2* __restrict__ rec,
                                             const int* __restrict__ bintot,
                                             int* __restrict__ rowp, float* __restrict__ dinv,
                                             int N, int NB) {
    __shared__ int bs[MAXSB];
    __shared__ int cnt[SB];
    __shared__ float deg[SB];
    __shared__ int wsum[4];
    int bin = blockIdx.x;
    int tid = threadIdx.x;
    bs_scan(bs, bintot, NB, tid);
    int e0 = bin ? bs[bin - 1] : 0;
    int e1 = bs[bin];
    cnt[tid] = 0; cnt[tid + 256] = 0;
    deg[tid] = 0.f; deg[tid + 256] = 0.f;
    __syncthreads();
    for (int e = e0 + tid; e < e1; e += 256) {
        int2 v = rec[e];
        int rl = (v.x >> 17) & 511;
        atomicAdd(&cnt[rl], 1);
        atomicAdd(&deg[rl], __int_as_float(v.y));
    }
    __syncthreads();
    int a = cnt[2 * tid], b = cnt[2 * tid + 1];
    int p = a + b;
    int lane = tid & 63, wv = tid >> 6;
    int incl = p;
    for (int off = 1; off < 64; off <<= 1) {
        int t = __shfl_up(incl, off);
        if (lane >= off) incl += t;
    }
    if (lane == 63) wsum[wv] = incl;
    __syncthreads();
    if (tid == 0) {
        int s = 0;
#pragma unroll
        for (int i = 0; i < 4; ++i) { int t = wsum[i]; wsum[i] = s; s += t; }
    }
    __syncthreads();
    int excl = incl - p + wsum[wv];
    int base = bin * SB;
    int rows = min(SB, N - base);
    if (2 * tid < rows) {
        rowp[base + 2 * tid] = e0 + excl;
        float d = deg[2 * tid];
        dinv[base + 2 * tid] = d > 0.f ? rsqrtf(d) : 0.f;
    }
    if (2 * tid + 1 < rows) {
        rowp[base + 2 * tid + 1] = e0 + excl + a;
        float d = deg[2 * tid + 1];
        dinv[base + 2 * tid + 1] = d > 0.f ? rsqrtf(d) : 0.f;
    }
    if (bin == NB - 1 && tid == 0) rowp[N] = e1;
}

// permutation in LDS -> coalesced, pre-scaled meta write
__global__ __launch_bounds__(256) void binD2(const int2* __restrict__ rec,
                                             const int* __restrict__ bintot,
                                             const int* __restrict__ rowp,
                                             const float* __restrict__ dinv,
                                             int2* __restrict__ meta, int N, int NB) {
    __shared__ int bs[MAXSB];
    __shared__ int cur[SB];
    __shared__ int perm[CAP];
    int bin = blockIdx.x;
    int tid = threadIdx.x;
    bs_scan(bs, bintot, NB, tid);
    int e0 = bin ? bs[bin - 1] : 0;
    int e1 = bs[bin];
    int base = bin * SB;
    int rows = min(SB, N - base);
    for (int i = tid; i < rows; i += 256) cur[i] = rowp[base + i];
    __syncthreads();
    for (int e = e0 + tid; e < e1; e += 256) {
        int2 v = rec[e];
        int rl = (v.x >> 17) & 511;
        int slot = atomicAdd(&cur[rl], 1);
        int so = slot - e0;
        if (so < CAP) {
            perm[so] = e - e0;
        } else {
            int c = v.x & 0x1FFFF;
            float ev = -dinv[base + rl] * __int_as_float(v.y) * dinv[c];
            meta[slot] = make_int2(c, __float_as_int(ev));
        }
    }
    __syncthreads();
    int lim = min(e1 - e0, CAP);
    for (int s = tid; s < lim; s += 256) {
        int2 v = rec[e0 + perm[s]];
        int rl = (v.x >> 17) & 511;
        int c = v.x & 0x1FFFF;
        float ev = -dinv[base + rl] * __int_as_float(v.y) * dinv[c];
        meta[e0 + s] = make_int2(c, __float_as_int(ev));
    }
}

// ================= degree counting sort -> row permutation =================

__global__ void dcount(const int* __restrict__ rowp, int* __restrict__ dh, int n) {
    int r = blockIdx.x * blockDim.x + threadIdx.x;
    if (r < n) {
        int d = min(rowp[r + 1] - rowp[r], 255);
        atomicAdd(&dh[(d << 6) | (r & 63)], 1);
    }
}

// generic exclusive scan over n ints (1024/block) — in-place safe
__global__ void scanB(const int* __restrict__ in, int* __restrict__ out,
                      int* __restrict__ part, int n) {
    __shared__ int sh[256];
    int tid = threadIdx.x;
    int base = blockIdx.x * 1024 + tid * 4;
    int v[4];
#pragma unroll
    for (int j = 0; j < 4; ++j) v[j] = (base + j < n) ? in[base + j] : 0;
    int s = v[0] + v[1] + v[2] + v[3];
    sh[tid] = s;
    __syncthreads();
    for (int off = 1; off < 256; off <<= 1) {
        int t = (tid >= off) ? sh[tid - off] : 0;
        __syncthreads();
        sh[tid] += t;
        __syncthreads();
    }
    int run = sh[tid] - s;
#pragma unroll
    for (int j = 0; j < 4; ++j) {
        if (base + j < n) out[base + j] = run;
        run += v[j];
    }
    if (tid == 255) part[blockIdx.x] = sh[255];
}

__global__ void scanP(int* __restrict__ part, int nb) {
    __shared__ int sh[256];
    int tid = threadIdx.x;
    int v = (tid < nb) ? part[tid] : 0;
    sh[tid] = v;
    __syncthreads();
    for (int off = 1; off < 256; off <<= 1) {
        int t = (tid >= off) ? sh[tid - off] : 0;
        __syncthreads();
        sh[tid] += t;
        __syncthreads();
    }
    if (tid < nb) part[tid] = sh[tid] - v;
}

__global__ void scanA(int* __restrict__ out, const int* __restrict__ part, int n) {
    int i = blockIdx.x * blockDim.x + threadIdx.x;
    if (i < n) out[i] += part[i >> 10];
}

__global__ void dplace(const int* __restrict__ rowp, int* __restrict__ dh,
                       int* __restrict__ order, int n) {
    int r = blockIdx.x * blockDim.x + threadIdx.x;
    if (r < n) {
        int d = min(rowp[r + 1] - rowp[r], 255);
        int slot = atomicAdd(&dh[(d << 6) | (r & 63)], 1);
        order[slot] = r;
    }
}

// ---------------- fused prep: W packs (first 4864 threads) + x->bf16 ----------------
__global__ void prep(const float* __restrict__ x, unsigned* __restrict__ xb, int n2,
                     const float* __restrict__ W1, const float* __restrict__ W3,
                     const float* __restrict__ W4, u16* __restrict__ Wpu,
                     u16* __restrict__ Wp3, u16* __restrict__ Wpp) {
    int gi = blockIdx.x * blockDim.x + threadIdx.x;
    if (gi < 3072) {
        int idx = gi;
        int lane = idx & 63;
        int nt = (idx >> 6) % 12;
        int kt = idx / 768;
        int krow = kt * 32 + (lane >> 4) * 8;
        int c = nt * 16 + (lane & 15);
        u16 tmp[8];
#pragma unroll
        for (int j = 0; j < 8; ++j) {
            int k = krow + j;
            float v;
            if (c < 64)       v = W1[(size_t)k * 64 + c] - W1[2 * 8192 + (size_t)k * 64 + c];
            else if (c < 128) v = W1[8192 + (size_t)k * 64 + (c - 64)];
            else              v = W1[2 * 8192 + (size_t)k * 64 + (c - 128)];
            tmp[j] = f2bf(v);
        }
        *reinterpret_cast<uint4*>(Wpu + (size_t)idx * 8) = *reinterpret_cast<const uint4*>(tmp);
    } else if (gi < 3072 + 1536) {
        int idx = gi - 3072;
        int lane = idx & 63;
        int nt = (idx >> 6) & 3;
        int kt = idx >> 8;
        int krow = kt * 32 + (lane >> 4) * 8;
        int c = nt * 16 + (lane & 15);
        u16 tmp[8];
#pragma unroll
        for (int j = 0; j < 8; ++j) tmp[j] = f2bf(W3[(size_t)(krow + j) * 64 + c]);
        *reinterpret_cast<uint4*>(Wp3 + (size_t)idx * 8) = *reinterpret_cast<const uint4*>(tmp);
    } else if (gi < 3072 + 1536 + 256) {
        int idx = gi - (3072 + 1536);
        int lane = idx & 63;
        int nt = (idx >> 6) & 1;
        int kt = idx >> 7;
        int krow = kt * 32 + (lane >> 4) * 8;
        int c = nt * 16 + (lane & 15);
        u16 tmp[8];
#pragma unroll
        for (int j = 0; j < 8; ++j) {
            int k = krow + j;
            float v = 0.f;
            if (c < 5)                  v = W4[(size_t)k * 5 + c] - W4[640 + (size_t)k * 5 + c];
            else if (c >= 8 && c < 13)  v = W4[320 + (size_t)k * 5 + (c - 8)];
            else if (c >= 16 && c < 21) v = W4[640 + (size_t)k * 5 + (c - 16)];
            tmp[j] = f2bf(v);
        }
        *reinterpret_cast<uint4*>(Wpp + (size_t)idx * 8) = *reinterpret_cast<const uint4*>(tmp);
    } else {
        int i = gi - 4864;
        if (i < n2) {
            float2 v = reinterpret_cast<const float2*>(x)[i];
            xb[i] = pack2(v.x, v.y);
        }
    }
}

// ---------------- SpMM (CSR) F=64, degree-ordered rows, bf16, fp32 acc ----------------
// MODE 0: y = acc ; 1: y = 2*acc + z ; 2: y = 2*acc - z ; 3: y = relu(acc + z + bias)
template <int MODE>
__global__ __launch_bounds__(256) void spmm64(const int* __restrict__ rp,
                                              const int* __restrict__ order,
                                              const int2* __restrict__ meta,
                                              const u16* __restrict__ x,
                                              const u16* __restrict__ z,
                                              const float* __restrict__ bias,
                                              u16* __restrict__ y, int n) {
    int g = blockIdx.x * 32 + (threadIdx.x >> 3);
    if (g >= n) return;
    int r = order[g];
    int f = (threadIdx.x & 7) * 8;
    int e0 = rp[r], e1 = rp[r + 1];
    float acc[8] = {0.f, 0.f, 0.f, 0.f, 0.f, 0.f, 0.f, 0.f};
    auto fma8 = [&](uint4 xv, float w) {
        acc[0] += w * bflo(xv.x); acc[1] += w * bfhi(xv.x);
        acc[2] += w * bflo(xv.y); acc[3] += w * bfhi(xv.y);
        acc[4] += w * bflo(xv.z); acc[5] += w * bfhi(xv.z);
        acc[6] += w * bflo(xv.w); acc[7] += w * bfhi(xv.w);
    };
    int e = e0;
    for (; e + 4 <= e1; e += 4) {
        int2 m0 = meta[e], m1 = meta[e + 1], m2 = meta[e + 2], m3 = meta[e + 3];
        uint4 v0 = *reinterpret_cast<const uint4*>(x + (size_t)m0.x * 64 + f);
        uint4 v1 = *reinterpret_cast<const uint4*>(x + (size_t)m1.x * 64 + f);
        uint4 v2 = *reinterpret_cast<const uint4*>(x + (size_t)m2.x * 64 + f);
        uint4 v3 = *reinterpret_cast<const uint4*>(x + (size_t)m3.x * 64 + f);
        fma8(v0, __int_as_float(m0.y));
        fma8(v1, __int_as_float(m1.y));
        fma8(v2, __int_as_float(m2.y));
        fma8(v3, __int_as_float(m3.y));
    }
    for (; e < e1; ++e) {
        int2 m = meta[e];
        uint4 xv = *reinterpret_cast<const uint4*>(x + (size_t)m.x * 64 + f);
        fma8(xv, __int_as_float(m.y));
    }
    if (MODE == 1 || MODE == 2) {
        uint4 zv = *reinterpret_cast<const uint4*>(z + (size_t)r * 64 + f);
        float zz[8] = {bflo(zv.x), bfhi(zv.x), bflo(zv.y), bfhi(zv.y),
                       bflo(zv.z), bfhi(zv.z), bflo(zv.w), bfhi(zv.w)};
#pragma unroll
        for (int j = 0; j < 8; ++j)
            acc[j] = (MODE == 1) ? 2.f * acc[j] + zz[j] : 2.f * acc[j] - zz[j];
    } else if (MODE == 3) {
        uint4 zv = *reinterpret_cast<const uint4*>(z + (size_t)r * 64 + f);
        float zz[8] = {bflo(zv.x), bfhi(zv.x), bflo(zv.y), bfhi(zv.y),
                       bflo(zv.z), bfhi(zv.z), bflo(zv.w), bfhi(zv.w)};
        float4 bl = *reinterpret_cast<const float4*>(bias + f);
        float4 bh = *reinterpret_cast<const float4*>(bias + f + 4);
        float bb[8] = {bl.x, bl.y, bl.z, bl.w, bh.x, bh.y, bh.z, bh.w};
#pragma unroll
        for (int j = 0; j < 8; ++j) acc[j] = fmaxf(acc[j] + zz[j] + bb[j], 0.f);
    }
    uint4 o;
    o.x = pack2(acc[0], acc[1]);
    o.y = pack2(acc[2], acc[3]);
    o.z = pack2(acc[4], acc[5]);
    o.w = pack2(acc[6], acc[7]);
    *reinterpret_cast<uint4*>(y + (size_t)r * 64 + f) = o;
}

// ---------------- SpMM width-8 (padded 5), 4 threads per row, degree-ordered ----------------
__device__ __forceinline__ void spmm8_acc(const int* rp, const int2* meta, const u16* x,
                                          int r, int t, float* acc) {
    int e0 = rp[r], e1 = rp[r + 1];
    auto fma8 = [&](uint4 xv, float w) {
        acc[0] += w * bflo(xv.x); acc[1] += w * bfhi(xv.x);
        acc[2] += w * bflo(xv.y); acc[3] += w * bfhi(xv.y);
        acc[4] += w * bflo(xv.z); acc[5] += w * bfhi(xv.z);
        acc[6] += w * bflo(xv.w); acc[7] += w * bfhi(xv.w);
    };
    int e = e0 + t;
    for (; e + 4 < e1; e += 8) {
        int2 m0 = meta[e], m1 = meta[e + 4];
        uint4 v0 = *reinterpret_cast<const uint4*>(x + (size_t)m0.x * 8);
        uint4 v1 = *reinterpret_cast<const uint4*>(x + (size_t)m1.x * 8);
        fma8(v0, __int_as_float(m0.y));
        fma8(v1, __int_as_float(m1.y));
    }
    for (; e < e1; e += 4) {
        int2 m = meta[e];
        uint4 xv = *reinterpret_cast<const uint4*>(x + (size_t)m.x * 8);
        fma8(xv, __int_as_float(m.y));
    }
#pragma unroll
    for (int j = 0; j < 8; ++j) acc[j] += __shfl_xor(acc[j], 1);
#pragma unroll
    for (int j = 0; j < 8; ++j) acc[j] += __shfl_xor(acc[j], 2);
}

// w5 = 2*L*p2 + p1
__global__ __launch_bounds__(256) void spmm8_p2(const int* __restrict__ rp,
                                                const int* __restrict__ order,
                                                const int2* __restrict__ meta,
                                                const u16* __restrict__ x,
                                                const u16* __restrict__ z,
                                                u16* __restrict__ y, int n) {
    int g = blockIdx.x * 64 + (threadIdx.x >> 2);
    if (g >= n) return;
    int r = order[g];
    int t = threadIdx.x & 3;
    float acc[8] = {0.f, 0.f, 0.f, 0.f, 0.f, 0.f, 0.f, 0.f};
    spmm8_acc(rp, meta, x, r, t, acc);
    if (t == 0) {
        uint4 zv = *reinterpret_cast<const uint4*>(z + (size_t)r * 8);
        float zz[8] = {bflo(zv.x), bfhi(zv.x), bflo(zv.y), bfhi(zv.y),
                       bflo(zv.z), bfhi(zv.z), bflo(zv.w), bfhi(zv.w)};
        uint4 o;
        o.x = pack2(2.f * acc[0] + zz[0], 2.f * acc[1] + zz[1]);
        o.y = pack2(2.f * acc[2] + zz[2], 2.f * acc[3] + zz[3]);
        o.z = pack2(2.f * acc[4] + zz[4], 2.f * acc[5] + zz[5]);
        o.w = pack2(2.f * acc[6] + zz[6], 2.f * acc[7] + zz[7]);
        *reinterpret_cast<uint4*>(y + (size_t)r * 8) = o;
    }
}

// out = log_softmax(L*w5 + p0 + b4) over 5 classes, fp32 out
__global__ __launch_bounds__(256) void spmm8_lsm(const int* __restrict__ rp,
                                                 const int* __restrict__ order,
                                                 const int2* __restrict__ meta,
                                                 const u16* __restrict__ x,
                                                 const u16* __restrict__ z,
                                                 const float* __restrict__ bias,
                                                 float* __restrict__ out, int n) {
    int g = blockIdx.x * 64 + (threadIdx.x >> 2);
    if (g >= n) return;
    int r = order[g];
    int t = threadIdx.x & 3;
    float acc[8] = {0.f, 0.f, 0.f, 0.f, 0.f, 0.f, 0.f, 0.f};
    spmm8_acc(rp, meta, x, r, t, acc);
    if (t == 0) {
        uint4 zv = *reinterpret_cast<const uint4*>(z + (size_t)r * 8);
        float zz[8] = {bflo(zv.x), bfhi(zv.x), bflo(zv.y), bfhi(zv.y),
                       bflo(zv.z), bfhi(zv.z), bflo(zv.w), bfhi(zv.w)};
        float val[5];
#pragma unroll
        for (int j = 0; j < 5; ++j) val[j] = acc[j] + zz[j] + bias[j];
        float mx = val[0];
#pragma unroll
        for (int j = 1; j < 5; ++j) mx = fmaxf(mx, val[j]);
        float s = 0.f;
#pragma unroll
        for (int j = 0; j < 5; ++j) s += expf(val[j] - mx);
        float l = logf(s);
#pragma unroll
        for (int j = 0; j < 5; ++j) out[(size_t)r * 5 + j] = val[j] - mx - l;
    }
}

// ---------------- MFMA GEMMs ----------------

__global__ __launch_bounds__(256) void gemm_u(const u16* __restrict__ A,
                                              const u16* __restrict__ Wp,
                                              u16* __restrict__ u0, u16* __restrict__ u1,
                                              u16* __restrict__ u2, int n) {
    int wave = threadIdx.x >> 6;
    int lane = threadIdx.x & 63;
    int r0 = blockIdx.x * 64 + wave * 16;
    int row = r0 + (lane & 15);
    int rowc = row < n ? row : n - 1;
    int kofs = (lane >> 4) * 8;
    f32x4 acc[12] = {};
    for (int kt = 0; kt < 4; ++kt) {
        bf16x8 a = *reinterpret_cast<const bf16x8*>(A + (size_t)rowc * 128 + kt * 32 + kofs);
        const u16* wb = Wp + (size_t)kt * 12 * 512 + (size_t)lane * 8;
#pragma unroll
        for (int nt = 0; nt < 12; ++nt) {
            bf16x8 b = *reinterpret_cast<const bf16x8*>(wb + nt * 512);
            acc[nt] = __builtin_amdgcn_mfma_f32_16x16x32_bf16(a, b, acc[nt], 0, 0, 0);
        }
    }
    int col = lane & 15;
    u16* U[3] = {u0, u1, u2};
#pragma unroll
    for (int nt = 0; nt < 12; ++nt) {
        u16* dst = U[nt >> 2];
        int cc = (nt & 3) * 16 + col;
#pragma unroll
        for (int i = 0; i < 4; ++i) {
            int rr = r0 + (lane >> 4) * 4 + i;
            if (rr < n) dst[(size_t)rr * 64 + cc] = f2bf(acc[nt][i]);
        }
    }
}

__global__ __launch_bounds__(256) void gemm3_mfma(const u16* __restrict__ A0,
                                                  const u16* __restrict__ A1,
                                                  const u16* __restrict__ A2,
                                                  const u16* __restrict__ Wp,
                                                  const float* __restrict__ bias,
                                                  u16* __restrict__ out, int n) {
    int wave = threadIdx.x >> 6;
    int lane = threadIdx.x & 63;
    int r0 = blockIdx.x * 64 + wave * 16;
    int row = r0 + (lane & 15);
    int rowc = row < n ? row : n - 1;
    int kofs = (lane >> 4) * 8;
    const u16* Ap[3] = {A0, A1, A2};
    f32x4 acc[4] = {};
    for (int kt = 0; kt < 6; ++kt) {
        const u16* Asrc = Ap[kt >> 1];
        int c0 = (kt & 1) * 32;
        bf16x8 a = *reinterpret_cast<const bf16x8*>(Asrc + (size_t)rowc * 64 + c0 + kofs);
        const u16* wb = Wp + (size_t)kt * 4 * 512 + (size_t)lane * 8;
#pragma unroll
        for (int nt = 0; nt < 4; ++nt) {
            bf16x8 b = *reinterpret_cast<const bf16x8*>(wb + nt * 512);
            acc[nt] = __builtin_amdgcn_mfma_f32_16x16x32_bf16(a, b, acc[nt], 0, 0, 0);
        }
    }
    int col = lane & 15;
#pragma unroll
    for (int nt = 0; nt < 4; ++nt) {
        float bb = bias[nt * 16 + col];
#pragma unroll
        for (int i = 0; i < 4; ++i) {
            int rr = r0 + (lane >> 4) * 4 + i;
            if (rr < n) {
                float v = fmaxf(acc[nt][i] + bb, 0.f);
                out[(size_t)rr * 64 + nt * 16 + col] = f2bf(v);
            }
        }
    }
}

__global__ __launch_bounds__(256) void gemm_proj(const u16* __restrict__ A,
                                                 const u16* __restrict__ Wp,
                                                 u16* __restrict__ p0, u16* __restrict__ p1,
                                                 u16* __restrict__ p2, int n) {
    int wave = threadIdx.x >> 6;
    int lane = threadIdx.x & 63;
    int r0 = blockIdx.x * 64 + wave * 16;
    int row = r0 + (lane & 15);
    int rowc = row < n ? row : n - 1;
    int kofs = (lane >> 4) * 8;
    f32x4 acc[2] = {};
    for (int kt = 0; kt < 2; ++kt) {
        bf16x8 a = *reinterpret_cast<const bf16x8*>(A + (size_t)rowc * 64 + kt * 32 + kofs);
        const u16* wb = Wp + (size_t)kt * 2 * 512 + (size_t)lane * 8;
#pragma unroll
        for (int nt = 0; nt < 2; ++nt) {
            bf16x8 b = *reinterpret_cast<const bf16x8*>(wb + nt * 512);
            acc[nt] = __builtin_amdgcn_mfma_f32_16x16x32_bf16(a, b, acc[nt], 0, 0, 0);
        }
    }
    int col = lane & 15;
    u16* P[3] = {p0, p1, p2};
#pragma unroll
    for (int nt = 0; nt < 2; ++nt) {
        int c = nt * 16 + col;
        if (c < 24) {
            u16* dst = P[c >> 3];
            int j = c & 7;
#pragma unroll
            for (int i = 0; i < 4; ++i) {
                int rr = r0 + (lane >> 4) * 4 + i;
                if (rr < n) dst[(size_t)rr * 8 + j] = f2bf(acc[nt][i]);
            }
        }
    }
}

// ---------------- launch ----------------

static inline size_t alignup(size_t v) { return (v + 255) & ~(size_t)255; }

extern "C" void kernel_launch(void* const* d_in, const int* in_sizes, int n_in,
                              void* d_out, int out_size, void* d_ws, size_t ws_size,
                              hipStream_t stream) {
    const float* x  = (const float*)d_in[0];
    const int*   ei = (const int*)d_in[1];
    const float* ew = (const float*)d_in[2];
    const float* W1 = (const float*)d_in[3];
    const float* b1 = (const float*)d_in[4];
    const float* W3 = (const float*)d_in[5];
    const float* b3 = (const float*)d_in[6];
    const float* W4 = (const float*)d_in[7];
    const float* b4 = (const float*)d_in[8];
    float* out = (float*)d_out;

    const int D = 128, H = 64;
    const int N = in_sizes[0] / D;
    const int E = in_sizes[2];
    const int* row = ei;
    const int* col = ei + E;

    char* ws = (char*)d_ws;
    size_t off = 0;
    auto alloc = [&](size_t bytes) { size_t o = off; off += alignup(bytes); return o; };

    float* dinv   = (float*)(ws + alloc((size_t)N * 4));
    int*   rowp   = (int*)  (ws + alloc((size_t)(N + 1) * 4));
    int*   bintot = (int*)  (ws + alloc(MAXSB * 4));
    int*   P      = (int*)  (ws + alloc((size_t)MAXSB * PB * 4));
    int*   dh     = (int*)  (ws + alloc((size_t)DHN * 4));
    int*   dpart  = (int*)  (ws + alloc(256 * 4));
    int*   order  = (int*)  (ws + alloc((size_t)N * 4));
    int2*  meta   = (int2*) (ws + alloc((size_t)E * 8));
    int2*  rec    = (int2*) (ws + alloc((size_t)E * 8));
    u16*   xb     = (u16*)  (ws + alloc((size_t)N * D * 2));
    u16*   A      = (u16*)  (ws + alloc((size_t)N * H * 2));
    u16*   B      = (u16*)  (ws + alloc((size_t)N * H * 2));
    u16*   C      = (u16*)  (ws + alloc((size_t)N * H * 2));
    u16*   Dd     = (u16*)  (ws + alloc((size_t)N * H * 2));
    u16*   P0     = (u16*)  (ws + alloc((size_t)N * 8 * 2));
    u16*   P1     = (u16*)  (ws + alloc((size_t)N * 8 * 2));
    u16*   P2     = (u16*)  (ws + alloc((size_t)N * 8 * 2));
    u16*   P3     = (u16*)  (ws + alloc((size_t)N * 8 * 2));
    u16*   Wpu    = (u16*)  (ws + alloc((size_t)4 * 12 * 512 * 2));
    u16*   Wp3    = (u16*)  (ws + alloc((size_t)6 * 4 * 512 * 2));
    u16*   Wpp    = (u16*)  (ws + alloc((size_t)2 * 2 * 512 * 2));

    const int NB = (N + SB - 1) / SB;     // super-bins (196 at N=100k)
    const int EB = (E + PB - 1) / PB;     // edges per partition block

    dim3 blk(256);
    int gN = (N + 255) / 256;

    hipMemsetAsync(dh, 0, (size_t)DHN * 4, stream);

    // ---- CSR build (no global hot atomics) ----
    binA<<<PB, blk, 0, stream>>>(row, P, E, NB, EB);
    binB1<<<NB, blk, 0, stream>>>(P, bintot);
    binC<<<PB, blk, 0, stream>>>(row, col, ew, P, bintot, rec, E, NB, EB);
    binD1<<<NB, blk, 0, stream>>>(rec, bintot, rowp, dinv, N, NB);
    binD2<<<NB, blk, 0, stream>>>(rec, bintot, rowp, dinv, meta, N, NB);

    // ---- degree counting sort -> order[] ----
    dcount<<<gN, blk, 0, stream>>>(rowp, dh, N);
    scanB<<<DHN / 1024, blk, 0, stream>>>(dh, dh, dpart, DHN);
    scanP<<<1, blk, 0, stream>>>(dpart, DHN / 1024);
    scanA<<<(DHN + 255) / 256, blk, 0, stream>>>(dh, dpart, DHN);
    dplace<<<gN, blk, 0, stream>>>(rowp, dh, order, N);

    // ---- prep (independent of CSR) ----
    int n2 = N * D / 2;
    prep<<<(n2 + 4864 + 255) / 256, blk, 0, stream>>>(x, (unsigned*)xb, n2, W1, W3, W4,
                                                      Wpu, Wp3, Wpp);

    int g64 = (N + 31) / 32;
    int gG  = (N + 63) / 64;
    int g8  = (N + 63) / 64;

    // ---- layer 1: u=[u0|u1|u2]=x@Wc ; w=2*L*u2+u1 ; h1=relu(L*w+u0+b1) ----
    gemm_u<<<gG, blk, 0, stream>>>(xb, Wpu, A, B, C, N);                          // u0=A u1=B u2=C
    spmm64<1><<<g64, blk, 0, stream>>>(rowp, order, meta, C, B, nullptr, Dd, N);  // w -> Dd
    spmm64<3><<<g64, blk, 0, stream>>>(rowp, order, meta, Dd, A, b1, B, N);       // h1 -> B

    // ---- layer 2: Ty1=L*h1 ; Ty2=2*L*Ty1-h1 ; h2=relu([h1|Ty1|Ty2]@W3+b3) ----
    spmm64<0><<<g64, blk, 0, stream>>>(rowp, order, meta, B, nullptr, nullptr, C, N);  // Ty1 -> C
    spmm64<2><<<g64, blk, 0, stream>>>(rowp, order, meta, C, B, nullptr, A, N);        // Ty2 -> A
    gemm3_mfma<<<gG, blk, 0, stream>>>(B, C, A, Wp3, b3, Dd, N);                       // h2 -> Dd

    // ---- layer 3: p=[p0|p1|p2]=h2@Wc3 ; w5=2*L*p2+p1 ; out=lsm(L*w5+p0+b4) ----
    gemm_proj<<<gG, blk, 0, stream>>>(Dd, Wpp, P0, P1, P2, N);
    spmm8_p2<<<g8, blk, 0, stream>>>(rowp, order, meta, P2, P1, P3, N);
    spmm8_lsm<<<g8, blk, 0, stream>>>(rowp, order, meta, P3, P0, b4, out, N);
}

// Round 11
// 324.289 us; speedup vs baseline: 1.1348x; 1.1348x over previous
//
#include <hip/hip_runtime.h>
#include <cstdint>
#include <cstddef>

typedef unsigned short u16;
typedef __attribute__((ext_vector_type(8))) short bf16x8;
typedef __attribute__((ext_vector_type(4))) float f32x4;

#define PB 1024    // partition blocks for binA/binC
#define MAXSB 256  // max super-bins (N <= 131072 at 512 rows/bin)
#define SB 512     // rows per super-bin
#define CAP 12288  // LDS perm capacity in binD2

// ---------------- bf16 helpers (RNE) ----------------
__device__ __forceinline__ float bflo(unsigned u) { return __uint_as_float(u << 16); }
__device__ __forceinline__ float bfhi(unsigned u) { return __uint_as_float(u & 0xFFFF0000u); }
__device__ __forceinline__ u16 f2bf(float f) {
    unsigned u = __float_as_uint(f);
    u += 0x7FFFu + ((u >> 16) & 1u);
    return (u16)(u >> 16);
}
__device__ __forceinline__ unsigned pack2(float a, float b) {
    return (unsigned)f2bf(a) | ((unsigned)f2bf(b) << 16);
}

// ================= CSR build: super-binned, zero global hot atomics =================
// super-bin = 512 rows (row>>9); record = {col | (row&511)<<17, w}

__global__ __launch_bounds__(256) void binA(const int* __restrict__ row, int* __restrict__ P,
                                            int E, int NB, int EB) {
    __shared__ int hist[MAXSB];
    int b = blockIdx.x;
    hist[threadIdx.x] = 0;
    __syncthreads();
    int e0 = b * EB, e1 = min(E, e0 + EB);
    for (int e = e0 + threadIdx.x; e < e1; e += 256)
        atomicAdd(&hist[row[e] >> 9], 1);
    __syncthreads();
    if (threadIdx.x < NB) P[(size_t)threadIdx.x * PB + b] = hist[threadIdx.x];
}

// per-bin exclusive scan over the PB=1024 block-partials; emit bin totals
__global__ __launch_bounds__(256) void binB1(int* __restrict__ P, int* __restrict__ bintot) {
    __shared__ int sh[256];
    int* p = P + (size_t)blockIdx.x * PB;
    int tid = threadIdx.x;
    int base = tid * 4;
    int v[4];
#pragma unroll
    for (int j = 0; j < 4; ++j) v[j] = p[base + j];
    int s = v[0] + v[1] + v[2] + v[3];
    sh[tid] = s;
    __syncthreads();
    for (int off = 1; off < 256; off <<= 1) {
        int t = (tid >= off) ? sh[tid - off] : 0;
        __syncthreads();
        sh[tid] += t;
        __syncthreads();
    }
    int run = sh[tid] - s;
#pragma unroll
    for (int j = 0; j < 4; ++j) { p[base + j] = run; run += v[j]; }
    if (tid == 255) bintot[blockIdx.x] = sh[255];
}

// helper: inclusive scan of bintot into bs[] (256 entries, in LDS)
__device__ __forceinline__ void bs_scan(int* bs, const int* bintot, int NB, int tid) {
    bs[tid] = (tid < NB) ? bintot[tid] : 0;
    __syncthreads();
    for (int off = 1; off < 256; off <<= 1) {
        int t = (tid >= off) ? bs[tid - off] : 0;
        __syncthreads();
        bs[tid] += t;
        __syncthreads();
    }
}

__global__ __launch_bounds__(256) void binC(const int* __restrict__ row, const int* __restrict__ col,
                                            const float* __restrict__ w, const int* __restrict__ P,
                                            const int* __restrict__ bintot, int2* __restrict__ rec,
                                            int E, int NB, int EB) {
    __shared__ int bs[MAXSB];
    __shared__ int cur[MAXSB];
    int b = blockIdx.x;
    int tid = threadIdx.x;
    bs_scan(bs, bintot, NB, tid);
    if (tid < NB) cur[tid] = (tid ? bs[tid - 1] : 0) + P[(size_t)tid * PB + b];
    __syncthreads();
    int e0 = b * EB, e1 = min(E, e0 + EB);
    for (int e = e0 + tid; e < e1; e += 256) {
        int r = row[e];
        int bin = r >> 9;
        int slot = atomicAdd(&cur[bin], 1);
        rec[slot] = make_int2(col[e] | ((r & 511) << 17), __float_as_int(w[e]));
    }
}

// per-bin counts + deg -> rowp + dinv (wave-level scan, 256 threads)
__global__ __launch_bounds__(256) void binD1(const int2* __restrict__ rec,
                                             const int* __restrict__ bintot,
                                             int* __restrict__ rowp, float* __restrict__ dinv,
                                             int N, int NB) {
    __shared__ int bs[MAXSB];
    __shared__ int cnt[SB];
    __shared__ float deg[SB];
    __shared__ int wsum[4];
    int bin = blockIdx.x;
    int tid = threadIdx.x;
    bs_scan(bs, bintot, NB, tid);
    int e0 = bin ? bs[bin - 1] : 0;
    int e1 = bs[bin];
    cnt[tid] = 0; cnt[tid + 256] = 0;
    deg[tid] = 0.f; deg[tid + 256] = 0.f;
    __syncthreads();
    for (int e = e0 + tid; e < e1; e += 256) {
        int2 v = rec[e];
        int rl = (v.x >> 17) & 511;
        atomicAdd(&cnt[rl], 1);
        atomicAdd(&deg[rl], __int_as_float(v.y));
    }
    __syncthreads();
    int a = cnt[2 * tid], b = cnt[2 * tid + 1];
    int p = a + b;
    int lane = tid & 63, wv = tid >> 6;
    int incl = p;
    for (int off = 1; off < 64; off <<= 1) {
        int t = __shfl_up(incl, off);
        if (lane >= off) incl += t;
    }
    if (lane == 63) wsum[wv] = incl;
    __syncthreads();
    if (tid == 0) {
        int s = 0;
#pragma unroll
        for (int i = 0; i < 4; ++i) { int t = wsum[i]; wsum[i] = s; s += t; }
    }
    __syncthreads();
    int excl = incl - p + wsum[wv];
    int base = bin * SB;
    int rows = min(SB, N - base);
    if (2 * tid < rows) {
        rowp[base + 2 * tid] = e0 + excl;
        float d = deg[2 * tid];
        dinv[base + 2 * tid] = d > 0.f ? rsqrtf(d) : 0.f;
    }
    if (2 * tid + 1 < rows) {
        rowp[base + 2 * tid + 1] = e0 + excl + a;
        float d = deg[2 * tid + 1];
        dinv[base + 2 * tid + 1] = d > 0.f ? rsqrtf(d) : 0.f;
    }
    if (bin == NB - 1 && tid == 0) rowp[N] = e1;
}

// permutation in LDS -> coalesced, pre-scaled meta write
__global__ __launch_bounds__(256) void binD2(const int2* __restrict__ rec,
                                             const int* __restrict__ bintot,
                                             const int* __restrict__ rowp,
                                             const float* __restrict__ dinv,
                                             int2* __restrict__ meta, int N, int NB) {
    __shared__ int bs[MAXSB];
    __shared__ int cur[SB];
    __shared__ int perm[CAP];
    int bin = blockIdx.x;
    int tid = threadIdx.x;
    bs_scan(bs, bintot, NB, tid);
    int e0 = bin ? bs[bin - 1] : 0;
    int e1 = bs[bin];
    int base = bin * SB;
    int rows = min(SB, N - base);
    for (int i = tid; i < rows; i += 256) cur[i] = rowp[base + i];
    __syncthreads();
    for (int e = e0 + tid; e < e1; e += 256) {
        int2 v = rec[e];
        int rl = (v.x >> 17) & 511;
        int slot = atomicAdd(&cur[rl], 1);
        int so = slot - e0;
        if (so < CAP) {
            perm[so] = e - e0;
        } else {
            int c = v.x & 0x1FFFF;
            float ev = -dinv[base + rl] * __int_as_float(v.y) * dinv[c];
            meta[slot] = make_int2(c, __float_as_int(ev));
        }
    }
    __syncthreads();
    int lim = min(e1 - e0, CAP);
    for (int s = tid; s < lim; s += 256) {
        int2 v = rec[e0 + perm[s]];
        int rl = (v.x >> 17) & 511;
        int c = v.x & 0x1FFFF;
        float ev = -dinv[base + rl] * __int_as_float(v.y) * dinv[c];
        meta[e0 + s] = make_int2(c, __float_as_int(ev));
    }
}

// window-local degree sort: order[bin*SB ..] = rows of bin sorted by degree.
// Keeps all spmm accesses within the 512-row window (locality preserved).
__global__ __launch_bounds__(256) void dsort(const int* __restrict__ rowp,
                                             int* __restrict__ order, int N) {
    __shared__ int hist[128], hs[128];
    int bin = blockIdx.x;
    int base = bin * SB;
    int rows = min(SB, N - base);
    int tid = threadIdx.x;
    if (tid < 128) hist[tid] = 0;
    __syncthreads();
    int d0 = -1, d1 = -1;
    int r0 = base + tid, r1 = base + tid + 256;
    if (tid < rows) d0 = min(rowp[r0 + 1] - rowp[r0], 127);
    if (tid + 256 < rows) d1 = min(rowp[r1 + 1] - rowp[r1], 127);
    if (d0 >= 0) atomicAdd(&hist[d0], 1);
    if (d1 >= 0) atomicAdd(&hist[d1], 1);
    __syncthreads();
    int cnt_k = (tid < 128) ? hist[tid] : 0;
    if (tid < 128) hs[tid] = cnt_k;
    __syncthreads();
    for (int off = 1; off < 128; off <<= 1) {
        int t = (tid >= off && tid < 128) ? hs[tid - off] : 0;
        __syncthreads();
        if (tid < 128) hs[tid] += t;
        __syncthreads();
    }
    if (tid < 128) hist[tid] = hs[tid] - cnt_k;  // exclusive start per degree key
    __syncthreads();
    if (d0 >= 0) { int s = atomicAdd(&hist[d0], 1); order[base + s] = r0; }
    if (d1 >= 0) { int s = atomicAdd(&hist[d1], 1); order[base + s] = r1; }
}

// ---------------- fused prep: W packs (first 4864 threads) + x->bf16 ----------------
__global__ void prep(const float* __restrict__ x, unsigned* __restrict__ xb, int n2,
                     const float* __restrict__ W1, const float* __restrict__ W3,
                     const float* __restrict__ W4, u16* __restrict__ Wpu,
                     u16* __restrict__ Wp3, u16* __restrict__ Wpp) {
    int gi = blockIdx.x * blockDim.x + threadIdx.x;
    if (gi < 3072) {
        int idx = gi;
        int lane = idx & 63;
        int nt = (idx >> 6) % 12;
        int kt = idx / 768;
        int krow = kt * 32 + (lane >> 4) * 8;
        int c = nt * 16 + (lane & 15);
        u16 tmp[8];
#pragma unroll
        for (int j = 0; j < 8; ++j) {
            int k = krow + j;
            float v;
            if (c < 64)       v = W1[(size_t)k * 64 + c] - W1[2 * 8192 + (size_t)k * 64 + c];
            else if (c < 128) v = W1[8192 + (size_t)k * 64 + (c - 64)];
            else              v = W1[2 * 8192 + (size_t)k * 64 + (c - 128)];
            tmp[j] = f2bf(v);
        }
        *reinterpret_cast<uint4*>(Wpu + (size_t)idx * 8) = *reinterpret_cast<const uint4*>(tmp);
    } else if (gi < 3072 + 1536) {
        int idx = gi - 3072;
        int lane = idx & 63;
        int nt = (idx >> 6) & 3;
        int kt = idx >> 8;
        int krow = kt * 32 + (lane >> 4) * 8;
        int c = nt * 16 + (lane & 15);
        u16 tmp[8];
#pragma unroll
        for (int j = 0; j < 8; ++j) tmp[j] = f2bf(W3[(size_t)(krow + j) * 64 + c]);
        *reinterpret_cast<uint4*>(Wp3 + (size_t)idx * 8) = *reinterpret_cast<const uint4*>(tmp);
    } else if (gi < 3072 + 1536 + 256) {
        int idx = gi - (3072 + 1536);
        int lane = idx & 63;
        int nt = (idx >> 6) & 1;
        int kt = idx >> 7;
        int krow = kt * 32 + (lane >> 4) * 8;
        int c = nt * 16 + (lane & 15);
        u16 tmp[8];
#pragma unroll
        for (int j = 0; j < 8; ++j) {
            int k = krow + j;
            float v = 0.f;
            if (c < 5)                  v = W4[(size_t)k * 5 + c] - W4[640 + (size_t)k * 5 + c];
            else if (c >= 8 && c < 13)  v = W4[320 + (size_t)k * 5 + (c - 8)];
            else if (c >= 16 && c < 21) v = W4[640 + (size_t)k * 5 + (c - 16)];
            tmp[j] = f2bf(v);
        }
        *reinterpret_cast<uint4*>(Wpp + (size_t)idx * 8) = *reinterpret_cast<const uint4*>(tmp);
    } else {
        int i = gi - 4864;
        if (i < n2) {
            float2 v = reinterpret_cast<const float2*>(x)[i];
            xb[i] = pack2(v.x, v.y);
        }
    }
}

// ---------------- SpMM (CSR) F=64, window-degree-ordered rows ----------------
// MODE 0: y = acc ; 1: y = 2*acc + z ; 2: y = 2*acc - z ; 3: y = relu(acc + z + bias)
template <int MODE>
__global__ __launch_bounds__(256) void spmm64(const int* __restrict__ rp,
                                              const int* __restrict__ order,
                                              const int2* __restrict__ meta,
                                              const u16* __restrict__ x,
                                              const u16* __restrict__ z,
                                              const float* __restrict__ bias,
                                              u16* __restrict__ y, int n) {
    int g = blockIdx.x * 32 + (threadIdx.x >> 3);
    if (g >= n) return;
    int r = order[g];
    int f = (threadIdx.x & 7) * 8;
    int e0 = rp[r], e1 = rp[r + 1];
    float acc[8] = {0.f, 0.f, 0.f, 0.f, 0.f, 0.f, 0.f, 0.f};
    auto fma8 = [&](uint4 xv, float w) {
        acc[0] += w * bflo(xv.x); acc[1] += w * bfhi(xv.x);
        acc[2] += w * bflo(xv.y); acc[3] += w * bfhi(xv.y);
        acc[4] += w * bflo(xv.z); acc[5] += w * bfhi(xv.z);
        acc[6] += w * bflo(xv.w); acc[7] += w * bfhi(xv.w);
    };
    int e = e0;
    for (; e + 4 <= e1; e += 4) {
        int2 m0 = meta[e], m1 = meta[e + 1], m2 = meta[e + 2], m3 = meta[e + 3];
        uint4 v0 = *reinterpret_cast<const uint4*>(x + (size_t)m0.x * 64 + f);
        uint4 v1 = *reinterpret_cast<const uint4*>(x + (size_t)m1.x * 64 + f);
        uint4 v2 = *reinterpret_cast<const uint4*>(x + (size_t)m2.x * 64 + f);
        uint4 v3 = *reinterpret_cast<const uint4*>(x + (size_t)m3.x * 64 + f);
        fma8(v0, __int_as_float(m0.y));
        fma8(v1, __int_as_float(m1.y));
        fma8(v2, __int_as_float(m2.y));
        fma8(v3, __int_as_float(m3.y));
    }
    for (; e < e1; ++e) {
        int2 m = meta[e];
        uint4 xv = *reinterpret_cast<const uint4*>(x + (size_t)m.x * 64 + f);
        fma8(xv, __int_as_float(m.y));
    }
    if (MODE == 1 || MODE == 2) {
        uint4 zv = *reinterpret_cast<const uint4*>(z + (size_t)r * 64 + f);
        float zz[8] = {bflo(zv.x), bfhi(zv.x), bflo(zv.y), bfhi(zv.y),
                       bflo(zv.z), bfhi(zv.z), bflo(zv.w), bfhi(zv.w)};
#pragma unroll
        for (int j = 0; j < 8; ++j)
            acc[j] = (MODE == 1) ? 2.f * acc[j] + zz[j] : 2.f * acc[j] - zz[j];
    } else if (MODE == 3) {
        uint4 zv = *reinterpret_cast<const uint4*>(z + (size_t)r * 64 + f);
        float zz[8] = {bflo(zv.x), bfhi(zv.x), bflo(zv.y), bfhi(zv.y),
                       bflo(zv.z), bfhi(zv.z), bflo(zv.w), bfhi(zv.w)};
        float4 bl = *reinterpret_cast<const float4*>(bias + f);
        float4 bh = *reinterpret_cast<const float4*>(bias + f + 4);
        float bb[8] = {bl.x, bl.y, bl.z, bl.w, bh.x, bh.y, bh.z, bh.w};
#pragma unroll
        for (int j = 0; j < 8; ++j) acc[j] = fmaxf(acc[j] + zz[j] + bb[j], 0.f);
    }
    uint4 o;
    o.x = pack2(acc[0], acc[1]);
    o.y = pack2(acc[2], acc[3]);
    o.z = pack2(acc[4], acc[5]);
    o.w = pack2(acc[6], acc[7]);
    *reinterpret_cast<uint4*>(y + (size_t)r * 64 + f) = o;
}

// ---------------- SpMM width-8 (padded 5), 4 threads per row ----------------
__device__ __forceinline__ void spmm8_acc(const int* rp, const int2* meta, const u16* x,
                                          int r, int t, float* acc) {
    int e0 = rp[r], e1 = rp[r + 1];
    auto fma8 = [&](uint4 xv, float w) {
        acc[0] += w * bflo(xv.x); acc[1] += w * bfhi(xv.x);
        acc[2] += w * bflo(xv.y); acc[3] += w * bfhi(xv.y);
        acc[4] += w * bflo(xv.z); acc[5] += w * bfhi(xv.z);
        acc[6] += w * bflo(xv.w); acc[7] += w * bfhi(xv.w);
    };
    int e = e0 + t;
    for (; e + 4 < e1; e += 8) {
        int2 m0 = meta[e], m1 = meta[e + 4];
        uint4 v0 = *reinterpret_cast<const uint4*>(x + (size_t)m0.x * 8);
        uint4 v1 = *reinterpret_cast<const uint4*>(x + (size_t)m1.x * 8);
        fma8(v0, __int_as_float(m0.y));
        fma8(v1, __int_as_float(m1.y));
    }
    for (; e < e1; e += 4) {
        int2 m = meta[e];
        uint4 xv = *reinterpret_cast<const uint4*>(x + (size_t)m.x * 8);
        fma8(xv, __int_as_float(m.y));
    }
#pragma unroll
    for (int j = 0; j < 8; ++j) acc[j] += __shfl_xor(acc[j], 1);
#pragma unroll
    for (int j = 0; j < 8; ++j) acc[j] += __shfl_xor(acc[j], 2);
}

// w5 = 2*L*p2 + p1
__global__ __launch_bounds__(256) void spmm8_p2(const int* __restrict__ rp,
                                                const int* __restrict__ order,
                                                const int2* __restrict__ meta,
                                                const u16* __restrict__ x,
                                                const u16* __restrict__ z,
                                                u16* __restrict__ y, int n) {
    int g = blockIdx.x * 64 + (threadIdx.x >> 2);
    if (g >= n) return;
    int r = order[g];
    int t = threadIdx.x & 3;
    float acc[8] = {0.f, 0.f, 0.f, 0.f, 0.f, 0.f, 0.f, 0.f};
    spmm8_acc(rp, meta, x, r, t, acc);
    if (t == 0) {
        uint4 zv = *reinterpret_cast<const uint4*>(z + (size_t)r * 8);
        float zz[8] = {bflo(zv.x), bfhi(zv.x), bflo(zv.y), bfhi(zv.y),
                       bflo(zv.z), bfhi(zv.z), bflo(zv.w), bfhi(zv.w)};
        uint4 o;
        o.x = pack2(2.f * acc[0] + zz[0], 2.f * acc[1] + zz[1]);
        o.y = pack2(2.f * acc[2] + zz[2], 2.f * acc[3] + zz[3]);
        o.z = pack2(2.f * acc[4] + zz[4], 2.f * acc[5] + zz[5]);
        o.w = pack2(2.f * acc[6] + zz[6], 2.f * acc[7] + zz[7]);
        *reinterpret_cast<uint4*>(y + (size_t)r * 8) = o;
    }
}

// out = log_softmax(L*w5 + p0 + b4) over 5 classes, fp32 out
__global__ __launch_bounds__(256) void spmm8_lsm(const int* __restrict__ rp,
                                                 const int* __restrict__ order,
                                                 const int2* __restrict__ meta,
                                                 const u16* __restrict__ x,
                                                 const u16* __restrict__ z,
                                                 const float* __restrict__ bias,
                                                 float* __restrict__ out, int n) {
    int g = blockIdx.x * 64 + (threadIdx.x >> 2);
    if (g >= n) return;
    int r = order[g];
    int t = threadIdx.x & 3;
    float acc[8] = {0.f, 0.f, 0.f, 0.f, 0.f, 0.f, 0.f, 0.f};
    spmm8_acc(rp, meta, x, r, t, acc);
    if (t == 0) {
        uint4 zv = *reinterpret_cast<const uint4*>(z + (size_t)r * 8);
        float zz[8] = {bflo(zv.x), bfhi(zv.x), bflo(zv.y), bfhi(zv.y),
                       bflo(zv.z), bfhi(zv.z), bflo(zv.w), bfhi(zv.w)};
        float val[5];
#pragma unroll
        for (int j = 0; j < 5; ++j) val[j] = acc[j] + zz[j] + bias[j];
        float mx = val[0];
#pragma unroll
        for (int j = 1; j < 5; ++j) mx = fmaxf(mx, val[j]);
        float s = 0.f;
#pragma unroll
        for (int j = 0; j < 5; ++j) s += expf(val[j] - mx);
        float l = logf(s);
#pragma unroll
        for (int j = 0; j < 5; ++j) out[(size_t)r * 5 + j] = val[j] - mx - l;
    }
}

// ---------------- MFMA GEMMs ----------------

__global__ __launch_bounds__(256) void gemm_u(const u16* __restrict__ A,
                                              const u16* __restrict__ Wp,
                                              u16* __restrict__ u0, u16* __restrict__ u1,
                                              u16* __restrict__ u2, int n) {
    int wave = threadIdx.x >> 6;
    int lane = threadIdx.x & 63;
    int r0 = blockIdx.x * 64 + wave * 16;
    int row = r0 + (lane & 15);
    int rowc = row < n ? row : n - 1;
    int kofs = (lane >> 4) * 8;
    f32x4 acc[12] = {};
    for (int kt = 0; kt < 4; ++kt) {
        bf16x8 a = *reinterpret_cast<const bf16x8*>(A + (size_t)rowc * 128 + kt * 32 + kofs);
        const u16* wb = Wp + (size_t)kt * 12 * 512 + (size_t)lane * 8;
#pragma unroll
        for (int nt = 0; nt < 12; ++nt) {
            bf16x8 b = *reinterpret_cast<const bf16x8*>(wb + nt * 512);
            acc[nt] = __builtin_amdgcn_mfma_f32_16x16x32_bf16(a, b, acc[nt], 0, 0, 0);
        }
    }
    int col = lane & 15;
    u16* U[3] = {u0, u1, u2};
#pragma unroll
    for (int nt = 0; nt < 12; ++nt) {
        u16* dst = U[nt >> 2];
        int cc = (nt & 3) * 16 + col;
#pragma unroll
        for (int i = 0; i < 4; ++i) {
            int rr = r0 + (lane >> 4) * 4 + i;
            if (rr < n) dst[(size_t)rr * 64 + cc] = f2bf(acc[nt][i]);
        }
    }
}

__global__ __launch_bounds__(256) void gemm3_mfma(const u16* __restrict__ A0,
                                                  const u16* __restrict__ A1,
                                                  const u16* __restrict__ A2,
                                                  const u16* __restrict__ Wp,
                                                  const float* __restrict__ bias,
                                                  u16* __restrict__ out, int n) {
    int wave = threadIdx.x >> 6;
    int lane = threadIdx.x & 63;
    int r0 = blockIdx.x * 64 + wave * 16;
    int row = r0 + (lane & 15);
    int rowc = row < n ? row : n - 1;
    int kofs = (lane >> 4) * 8;
    const u16* Ap[3] = {A0, A1, A2};
    f32x4 acc[4] = {};
    for (int kt = 0; kt < 6; ++kt) {
        const u16* Asrc = Ap[kt >> 1];
        int c0 = (kt & 1) * 32;
        bf16x8 a = *reinterpret_cast<const bf16x8*>(Asrc + (size_t)rowc * 64 + c0 + kofs);
        const u16* wb = Wp + (size_t)kt * 4 * 512 + (size_t)lane * 8;
#pragma unroll
        for (int nt = 0; nt < 4; ++nt) {
            bf16x8 b = *reinterpret_cast<const bf16x8*>(wb + nt * 512);
            acc[nt] = __builtin_amdgcn_mfma_f32_16x16x32_bf16(a, b, acc[nt], 0, 0, 0);
        }
    }
    int col = lane & 15;
#pragma unroll
    for (int nt = 0; nt < 4; ++nt) {
        float bb = bias[nt * 16 + col];
#pragma unroll
        for (int i = 0; i < 4; ++i) {
            int rr = r0 + (lane >> 4) * 4 + i;
            if (rr < n) {
                float v = fmaxf(acc[nt][i] + bb, 0.f);
                out[(size_t)rr * 64 + nt * 16 + col] = f2bf(v);
            }
        }
    }
}

__global__ __launch_bounds__(256) void gemm_proj(const u16* __restrict__ A,
                                                 const u16* __restrict__ Wp,
                                                 u16* __restrict__ p0, u16* __restrict__ p1,
                                                 u16* __restrict__ p2, int n) {
    int wave = threadIdx.x >> 6;
    int lane = threadIdx.x & 63;
    int r0 = blockIdx.x * 64 + wave * 16;
    int row = r0 + (lane & 15);
    int rowc = row < n ? row : n - 1;
    int kofs = (lane >> 4) * 8;
    f32x4 acc[2] = {};
    for (int kt = 0; kt < 2; ++kt) {
        bf16x8 a = *reinterpret_cast<const bf16x8*>(A + (size_t)rowc * 64 + kt * 32 + kofs);
        const u16* wb = Wp + (size_t)kt * 2 * 512 + (size_t)lane * 8;
#pragma unroll
        for (int nt = 0; nt < 2; ++nt) {
            bf16x8 b = *reinterpret_cast<const bf16x8*>(wb + nt * 512);
            acc[nt] = __builtin_amdgcn_mfma_f32_16x16x32_bf16(a, b, acc[nt], 0, 0, 0);
        }
    }
    int col = lane & 15;
    u16* P[3] = {p0, p1, p2};
#pragma unroll
    for (int nt = 0; nt < 2; ++nt) {
        int c = nt * 16 + col;
        if (c < 24) {
            u16* dst = P[c >> 3];
            int j = c & 7;
#pragma unroll
            for (int i = 0; i < 4; ++i) {
                int rr = r0 + (lane >> 4) * 4 + i;
                if (rr < n) dst[(size_t)rr * 8 + j] = f2bf(acc[nt][i]);
            }
        }
    }
}

// ---------------- launch ----------------

static inline size_t alignup(size_t v) { return (v + 255) & ~(size_t)255; }

extern "C" void kernel_launch(void* const* d_in, const int* in_sizes, int n_in,
                              void* d_out, int out_size, void* d_ws, size_t ws_size,
                              hipStream_t stream) {
    const float* x  = (const float*)d_in[0];
    const int*   ei = (const int*)d_in[1];
    const float* ew = (const float*)d_in[2];
    const float* W1 = (const float*)d_in[3];
    const float* b1 = (const float*)d_in[4];
    const float* W3 = (const float*)d_in[5];
    const float* b3 = (const float*)d_in[6];
    const float* W4 = (const float*)d_in[7];
    const float* b4 = (const float*)d_in[8];
    float* out = (float*)d_out;

    const int D = 128, H = 64;
    const int N = in_sizes[0] / D;
    const int E = in_sizes[2];
    const int* row = ei;
    const int* col = ei + E;

    char* ws = (char*)d_ws;
    size_t off = 0;
    auto alloc = [&](size_t bytes) { size_t o = off; off += alignup(bytes); return o; };

    float* dinv   = (float*)(ws + alloc((size_t)N * 4));
    int*   rowp   = (int*)  (ws + alloc((size_t)(N + 1) * 4));
    int*   bintot = (int*)  (ws + alloc(MAXSB * 4));
    int*   P      = (int*)  (ws + alloc((size_t)MAXSB * PB * 4));
    int*   order  = (int*)  (ws + alloc((size_t)N * 4));
    int2*  meta   = (int2*) (ws + alloc((size_t)E * 8));
    int2*  rec    = (int2*) (ws + alloc((size_t)E * 8));
    u16*   xb     = (u16*)  (ws + alloc((size_t)N * D * 2));
    u16*   A      = (u16*)  (ws + alloc((size_t)N * H * 2));
    u16*   B      = (u16*)  (ws + alloc((size_t)N * H * 2));
    u16*   C      = (u16*)  (ws + alloc((size_t)N * H * 2));
    u16*   Dd     = (u16*)  (ws + alloc((size_t)N * H * 2));
    u16*   P0     = (u16*)  (ws + alloc((size_t)N * 8 * 2));
    u16*   P1     = (u16*)  (ws + alloc((size_t)N * 8 * 2));
    u16*   P2     = (u16*)  (ws + alloc((size_t)N * 8 * 2));
    u16*   P3     = (u16*)  (ws + alloc((size_t)N * 8 * 2));
    u16*   Wpu    = (u16*)  (ws + alloc((size_t)4 * 12 * 512 * 2));
    u16*   Wp3    = (u16*)  (ws + alloc((size_t)6 * 4 * 512 * 2));
    u16*   Wpp    = (u16*)  (ws + alloc((size_t)2 * 2 * 512 * 2));

    const int NB = (N + SB - 1) / SB;     // super-bins (196 at N=100k)
    const int EB = (E + PB - 1) / PB;     // edges per partition block

    dim3 blk(256);

    // ---- CSR build (no global hot atomics) ----
    binA<<<PB, blk, 0, stream>>>(row, P, E, NB, EB);
    binB1<<<NB, blk, 0, stream>>>(P, bintot);
    binC<<<PB, blk, 0, stream>>>(row, col, ew, P, bintot, rec, E, NB, EB);
    binD1<<<NB, blk, 0, stream>>>(rec, bintot, rowp, dinv, N, NB);
    binD2<<<NB, blk, 0, stream>>>(rec, bintot, rowp, dinv, meta, N, NB);
    dsort<<<NB, blk, 0, stream>>>(rowp, order, N);   // window-local degree order

    // ---- prep (independent of CSR) ----
    int n2 = N * D / 2;
    prep<<<(n2 + 4864 + 255) / 256, blk, 0, stream>>>(x, (unsigned*)xb, n2, W1, W3, W4,
                                                      Wpu, Wp3, Wpp);

    int g64 = (N + 31) / 32;
    int gG  = (N + 63) / 64;
    int g8  = (N + 63) / 64;

    // ---- layer 1: u=[u0|u1|u2]=x@Wc ; w=2*L*u2+u1 ; h1=relu(L*w+u0+b1) ----
    gemm_u<<<gG, blk, 0, stream>>>(xb, Wpu, A, B, C, N);                          // u0=A u1=B u2=C
    spmm64<1><<<g64, blk, 0, stream>>>(rowp, order, meta, C, B, nullptr, Dd, N);  // w -> Dd
    spmm64<3><<<g64, blk, 0, stream>>>(rowp, order, meta, Dd, A, b1, B, N);       // h1 -> B

    // ---- layer 2: Ty1=L*h1 ; Ty2=2*L*Ty1-h1 ; h2=relu([h1|Ty1|Ty2]@W3+b3) ----
    spmm64<0><<<g64, blk, 0, stream>>>(rowp, order, meta, B, nullptr, nullptr, C, N);  // Ty1 -> C
    spmm64<2><<<g64, blk, 0, stream>>>(rowp, order, meta, C, B, nullptr, A, N);        // Ty2 -> A
    gemm3_mfma<<<gG, blk, 0, stream>>>(B, C, A, Wp3, b3, Dd, N);                       // h2 -> Dd

    // ---- layer 3: p=[p0|p1|p2]=h2@Wc3 ; w5=2*L*p2+p1 ; out=lsm(L*w5+p0+b4) ----
    gemm_proj<<<gG, blk, 0, stream>>>(Dd, Wpp, P0, P1, P2, N);
    spmm8_p2<<<g8, blk, 0, stream>>>(rowp, order, meta, P2, P1, P3, N);
    spmm8_lsm<<<g8, blk, 0, stream>>>(rowp, order, meta, P3, P0, b4, out, N);
}

// Round 12
// 285.246 us; speedup vs baseline: 1.2902x; 1.1369x over previous
//
#include <hip/hip_runtime.h>
#include <cstdint>
#include <cstddef>

typedef unsigned short u16;
typedef __attribute__((ext_vector_type(8))) short bf16x8;
typedef __attribute__((ext_vector_type(4))) float f32x4;

#define PB 1024    // partition blocks for binA/binC
#define MAXSB 256  // max super-bins (N <= 131072 at 512 rows/bin)
#define SB 512     // rows per super-bin
#define CAP 12288  // LDS perm capacity in binD2

// ---------------- bf16 helpers (RNE) ----------------
__device__ __forceinline__ float bflo(unsigned u) { return __uint_as_float(u << 16); }
__device__ __forceinline__ float bfhi(unsigned u) { return __uint_as_float(u & 0xFFFF0000u); }
__device__ __forceinline__ u16 f2bf(float f) {
    unsigned u = __float_as_uint(f);
    u += 0x7FFFu + ((u >> 16) & 1u);
    return (u16)(u >> 16);
}
__device__ __forceinline__ unsigned pack2(float a, float b) {
    return (unsigned)f2bf(a) | ((unsigned)f2bf(b) << 16);
}

// ================= CSR build: super-binned, zero global hot atomics =================
// super-bin = 512 rows (row>>9); record = {col | (row&511)<<17, w}

__global__ __launch_bounds__(256) void binA(const int* __restrict__ row, int* __restrict__ P,
                                            int E, int NB, int EB) {
    __shared__ int hist[MAXSB];
    int b = blockIdx.x;
    hist[threadIdx.x] = 0;
    __syncthreads();
    int e0 = b * EB, e1 = min(E, e0 + EB);
    for (int e = e0 + threadIdx.x; e < e1; e += 256)
        atomicAdd(&hist[row[e] >> 9], 1);
    __syncthreads();
    if (threadIdx.x < NB) P[(size_t)threadIdx.x * PB + b] = hist[threadIdx.x];
}

// per-bin exclusive scan over the PB=1024 block-partials; emit bin totals
__global__ __launch_bounds__(256) void binB1(int* __restrict__ P, int* __restrict__ bintot) {
    __shared__ int sh[256];
    int* p = P + (size_t)blockIdx.x * PB;
    int tid = threadIdx.x;
    int base = tid * 4;
    int v[4];
#pragma unroll
    for (int j = 0; j < 4; ++j) v[j] = p[base + j];
    int s = v[0] + v[1] + v[2] + v[3];
    sh[tid] = s;
    __syncthreads();
    for (int off = 1; off < 256; off <<= 1) {
        int t = (tid >= off) ? sh[tid - off] : 0;
        __syncthreads();
        sh[tid] += t;
        __syncthreads();
    }
    int run = sh[tid] - s;
#pragma unroll
    for (int j = 0; j < 4; ++j) { p[base + j] = run; run += v[j]; }
    if (tid == 255) bintot[blockIdx.x] = sh[255];
}

// helper: inclusive scan of bintot into bs[] (256 entries, in LDS)
__device__ __forceinline__ void bs_scan(int* bs, const int* bintot, int NB, int tid) {
    bs[tid] = (tid < NB) ? bintot[tid] : 0;
    __syncthreads();
    for (int off = 1; off < 256; off <<= 1) {
        int t = (tid >= off) ? bs[tid - off] : 0;
        __syncthreads();
        bs[tid] += t;
        __syncthreads();
    }
}

__global__ __launch_bounds__(256) void binC(const int* __restrict__ row, const int* __restrict__ col,
                                            const float* __restrict__ w, const int* __restrict__ P,
                                            const int* __restrict__ bintot, int2* __restrict__ rec,
                                            int E, int NB, int EB) {
    __shared__ int bs[MAXSB];
    __shared__ int cur[MAXSB];
    int b = blockIdx.x;
    int tid = threadIdx.x;
    bs_scan(bs, bintot, NB, tid);
    if (tid < NB) cur[tid] = (tid ? bs[tid - 1] : 0) + P[(size_t)tid * PB + b];
    __syncthreads();
    int e0 = b * EB, e1 = min(E, e0 + EB);
    for (int e = e0 + tid; e < e1; e += 256) {
        int r = row[e];
        int bin = r >> 9;
        int slot = atomicAdd(&cur[bin], 1);
        rec[slot] = make_int2(col[e] | ((r & 511) << 17), __float_as_int(w[e]));
    }
}

// per-bin counts + deg -> rowp + dinv (wave-level scan, 256 threads)
__global__ __launch_bounds__(256) void binD1(const int2* __restrict__ rec,
                                             const int* __restrict__ bintot,
                                             int* __restrict__ rowp, float* __restrict__ dinv,
                                             int N, int NB) {
    __shared__ int bs[MAXSB];
    __shared__ int cnt[SB];
    __shared__ float deg[SB];
    __shared__ int wsum[4];
    int bin = blockIdx.x;
    int tid = threadIdx.x;
    bs_scan(bs, bintot, NB, tid);
    int e0 = bin ? bs[bin - 1] : 0;
    int e1 = bs[bin];
    cnt[tid] = 0; cnt[tid + 256] = 0;
    deg[tid] = 0.f; deg[tid + 256] = 0.f;
    __syncthreads();
    for (int e = e0 + tid; e < e1; e += 256) {
        int2 v = rec[e];
        int rl = (v.x >> 17) & 511;
        atomicAdd(&cnt[rl], 1);
        atomicAdd(&deg[rl], __int_as_float(v.y));
    }
    __syncthreads();
    int a = cnt[2 * tid], b = cnt[2 * tid + 1];
    int p = a + b;
    int lane = tid & 63, wv = tid >> 6;
    int incl = p;
    for (int off = 1; off < 64; off <<= 1) {
        int t = __shfl_up(incl, off);
        if (lane >= off) incl += t;
    }
    if (lane == 63) wsum[wv] = incl;
    __syncthreads();
    if (tid == 0) {
        int s = 0;
#pragma unroll
        for (int i = 0; i < 4; ++i) { int t = wsum[i]; wsum[i] = s; s += t; }
    }
    __syncthreads();
    int excl = incl - p + wsum[wv];
    int base = bin * SB;
    int rows = min(SB, N - base);
    if (2 * tid < rows) {
        rowp[base + 2 * tid] = e0 + excl;
        float d = deg[2 * tid];
        dinv[base + 2 * tid] = d > 0.f ? rsqrtf(d) : 0.f;
    }
    if (2 * tid + 1 < rows) {
        rowp[base + 2 * tid + 1] = e0 + excl + a;
        float d = deg[2 * tid + 1];
        dinv[base + 2 * tid + 1] = d > 0.f ? rsqrtf(d) : 0.f;
    }
    if (bin == NB - 1 && tid == 0) rowp[N] = e1;
}

// permutation in LDS -> coalesced, pre-scaled meta write
__global__ __launch_bounds__(256) void binD2(const int2* __restrict__ rec,
                                             const int* __restrict__ bintot,
                                             const int* __restrict__ rowp,
                                             const float* __restrict__ dinv,
                                             int2* __restrict__ meta, int N, int NB) {
    __shared__ int bs[MAXSB];
    __shared__ int cur[SB];
    __shared__ int perm[CAP];
    int bin = blockIdx.x;
    int tid = threadIdx.x;
    bs_scan(bs, bintot, NB, tid);
    int e0 = bin ? bs[bin - 1] : 0;
    int e1 = bs[bin];
    int base = bin * SB;
    int rows = min(SB, N - base);
    for (int i = tid; i < rows; i += 256) cur[i] = rowp[base + i];
    __syncthreads();
    for (int e = e0 + tid; e < e1; e += 256) {
        int2 v = rec[e];
        int rl = (v.x >> 17) & 511;
        int slot = atomicAdd(&cur[rl], 1);
        int so = slot - e0;
        if (so < CAP) {
            perm[so] = e - e0;
        } else {
            int c = v.x & 0x1FFFF;
            float ev = -dinv[base + rl] * __int_as_float(v.y) * dinv[c];
            meta[slot] = make_int2(c, __float_as_int(ev));
        }
    }
    __syncthreads();
    int lim = min(e1 - e0, CAP);
    for (int s = tid; s < lim; s += 256) {
        int2 v = rec[e0 + perm[s]];
        int rl = (v.x >> 17) & 511;
        int c = v.x & 0x1FFFF;
        float ev = -dinv[base + rl] * __int_as_float(v.y) * dinv[c];
        meta[e0 + s] = make_int2(c, __float_as_int(ev));
    }
}

// ---------------- fused prep: W packs (first 4864 threads) + x->bf16 ----------------
__global__ void prep(const float* __restrict__ x, unsigned* __restrict__ xb, int n2,
                     const float* __restrict__ W1, const float* __restrict__ W3,
                     const float* __restrict__ W4, u16* __restrict__ Wpu,
                     u16* __restrict__ Wp3, u16* __restrict__ Wpp) {
    int gi = blockIdx.x * blockDim.x + threadIdx.x;
    if (gi < 3072) {
        int idx = gi;
        int lane = idx & 63;
        int nt = (idx >> 6) % 12;
        int kt = idx / 768;
        int krow = kt * 32 + (lane >> 4) * 8;
        int c = nt * 16 + (lane & 15);
        u16 tmp[8];
#pragma unroll
        for (int j = 0; j < 8; ++j) {
            int k = krow + j;
            float v;
            if (c < 64)       v = W1[(size_t)k * 64 + c] - W1[2 * 8192 + (size_t)k * 64 + c];
            else if (c < 128) v = W1[8192 + (size_t)k * 64 + (c - 64)];
            else              v = W1[2 * 8192 + (size_t)k * 64 + (c - 128)];
            tmp[j] = f2bf(v);
        }
        *reinterpret_cast<uint4*>(Wpu + (size_t)idx * 8) = *reinterpret_cast<const uint4*>(tmp);
    } else if (gi < 3072 + 1536) {
        int idx = gi - 3072;
        int lane = idx & 63;
        int nt = (idx >> 6) & 3;
        int kt = idx >> 8;
        int krow = kt * 32 + (lane >> 4) * 8;
        int c = nt * 16 + (lane & 15);
        u16 tmp[8];
#pragma unroll
        for (int j = 0; j < 8; ++j) tmp[j] = f2bf(W3[(size_t)(krow + j) * 64 + c]);
        *reinterpret_cast<uint4*>(Wp3 + (size_t)idx * 8) = *reinterpret_cast<const uint4*>(tmp);
    } else if (gi < 3072 + 1536 + 256) {
        int idx = gi - (3072 + 1536);
        int lane = idx & 63;
        int nt = (idx >> 6) & 1;
        int kt = idx >> 7;
        int krow = kt * 32 + (lane >> 4) * 8;
        int c = nt * 16 + (lane & 15);
        u16 tmp[8];
#pragma unroll
        for (int j = 0; j < 8; ++j) {
            int k = krow + j;
            float v = 0.f;
            if (c < 5)                  v = W4[(size_t)k * 5 + c] - W4[640 + (size_t)k * 5 + c];
            else if (c >= 8 && c < 13)  v = W4[320 + (size_t)k * 5 + (c - 8)];
            else if (c >= 16 && c < 21) v = W4[640 + (size_t)k * 5 + (c - 16)];
            tmp[j] = f2bf(v);
        }
        *reinterpret_cast<uint4*>(Wpp + (size_t)idx * 8) = *reinterpret_cast<const uint4*>(tmp);
    } else {
        int i = gi - 4864;
        if (i < n2) {
            float2 v = reinterpret_cast<const float2*>(x)[i];
            xb[i] = pack2(v.x, v.y);
        }
    }
}

// ---------------- SpMM (CSR) F=64, 16 threads/row (2 edge-groups x 8 f-threads) ----------------
// MODE 0: y = acc ; 1: y = 2*acc + z ; 2: y = 2*acc - z ; 3: y = relu(acc + z + bias)
template <int MODE>
__global__ __launch_bounds__(256) void spmm64(const int* __restrict__ rp,
                                              const int2* __restrict__ meta,
                                              const u16* __restrict__ x,
                                              const u16* __restrict__ z,
                                              const float* __restrict__ bias,
                                              u16* __restrict__ y, int n) {
    int r = blockIdx.x * 16 + (threadIdx.x >> 4);
    if (r >= n) return;
    int sub = (threadIdx.x >> 3) & 1;   // edge half (lane bit 3)
    int f = (threadIdx.x & 7) * 8;
    int e0 = rp[r], e1 = rp[r + 1];
    float acc[8] = {0.f, 0.f, 0.f, 0.f, 0.f, 0.f, 0.f, 0.f};
    auto fma8 = [&](uint4 xv, float w) {
        acc[0] += w * bflo(xv.x); acc[1] += w * bfhi(xv.x);
        acc[2] += w * bflo(xv.y); acc[3] += w * bfhi(xv.y);
        acc[4] += w * bflo(xv.z); acc[5] += w * bfhi(xv.z);
        acc[6] += w * bflo(xv.w); acc[7] += w * bfhi(xv.w);
    };
    // this half walks edges e0+sub, e0+sub+2, ... ; unroll x4 -> 4 gathers in flight
    int e = e0 + sub;
    for (; e + 6 < e1; e += 8) {
        int2 m0 = meta[e], m1 = meta[e + 2], m2 = meta[e + 4], m3 = meta[e + 6];
        uint4 v0 = *reinterpret_cast<const uint4*>(x + (size_t)m0.x * 64 + f);
        uint4 v1 = *reinterpret_cast<const uint4*>(x + (size_t)m1.x * 64 + f);
        uint4 v2 = *reinterpret_cast<const uint4*>(x + (size_t)m2.x * 64 + f);
        uint4 v3 = *reinterpret_cast<const uint4*>(x + (size_t)m3.x * 64 + f);
        fma8(v0, __int_as_float(m0.y));
        fma8(v1, __int_as_float(m1.y));
        fma8(v2, __int_as_float(m2.y));
        fma8(v3, __int_as_float(m3.y));
    }
    for (; e < e1; e += 2) {
        int2 m = meta[e];
        uint4 xv = *reinterpret_cast<const uint4*>(x + (size_t)m.x * 64 + f);
        fma8(xv, __int_as_float(m.y));
    }
    // combine the two edge halves (same wave: lane bit 3)
#pragma unroll
    for (int j = 0; j < 8; ++j) acc[j] += __shfl_xor(acc[j], 8);
    if (sub) return;
    if (MODE == 1 || MODE == 2) {
        uint4 zv = *reinterpret_cast<const uint4*>(z + (size_t)r * 64 + f);
        float zz[8] = {bflo(zv.x), bfhi(zv.x), bflo(zv.y), bfhi(zv.y),
                       bflo(zv.z), bfhi(zv.z), bflo(zv.w), bfhi(zv.w)};
#pragma unroll
        for (int j = 0; j < 8; ++j)
            acc[j] = (MODE == 1) ? 2.f * acc[j] + zz[j] : 2.f * acc[j] - zz[j];
    } else if (MODE == 3) {
        uint4 zv = *reinterpret_cast<const uint4*>(z + (size_t)r * 64 + f);
        float zz[8] = {bflo(zv.x), bfhi(zv.x), bflo(zv.y), bfhi(zv.y),
                       bflo(zv.z), bfhi(zv.z), bflo(zv.w), bfhi(zv.w)};
        float4 bl = *reinterpret_cast<const float4*>(bias + f);
        float4 bh = *reinterpret_cast<const float4*>(bias + f + 4);
        float bb[8] = {bl.x, bl.y, bl.z, bl.w, bh.x, bh.y, bh.z, bh.w};
#pragma unroll
        for (int j = 0; j < 8; ++j) acc[j] = fmaxf(acc[j] + zz[j] + bb[j], 0.f);
    }
    uint4 o;
    o.x = pack2(acc[0], acc[1]);
    o.y = pack2(acc[2], acc[3]);
    o.z = pack2(acc[4], acc[5]);
    o.w = pack2(acc[6], acc[7]);
    *reinterpret_cast<uint4*>(y + (size_t)r * 64 + f) = o;
}

// ---------------- SpMM width-8 (padded 5), 4 threads per row ----------------
__device__ __forceinline__ void spmm8_acc(const int* rp, const int2* meta, const u16* x,
                                          int r, int t, float* acc) {
    int e0 = rp[r], e1 = rp[r + 1];
    auto fma8 = [&](uint4 xv, float w) {
        acc[0] += w * bflo(xv.x); acc[1] += w * bfhi(xv.x);
        acc[2] += w * bflo(xv.y); acc[3] += w * bfhi(xv.y);
        acc[4] += w * bflo(xv.z); acc[5] += w * bfhi(xv.z);
        acc[6] += w * bflo(xv.w); acc[7] += w * bfhi(xv.w);
    };
    int e = e0 + t;
    for (; e + 4 < e1; e += 8) {
        int2 m0 = meta[e], m1 = meta[e + 4];
        uint4 v0 = *reinterpret_cast<const uint4*>(x + (size_t)m0.x * 8);
        uint4 v1 = *reinterpret_cast<const uint4*>(x + (size_t)m1.x * 8);
        fma8(v0, __int_as_float(m0.y));
        fma8(v1, __int_as_float(m1.y));
    }
    for (; e < e1; e += 4) {
        int2 m = meta[e];
        uint4 xv = *reinterpret_cast<const uint4*>(x + (size_t)m.x * 8);
        fma8(xv, __int_as_float(m.y));
    }
#pragma unroll
    for (int j = 0; j < 8; ++j) acc[j] += __shfl_xor(acc[j], 1);
#pragma unroll
    for (int j = 0; j < 8; ++j) acc[j] += __shfl_xor(acc[j], 2);
}

// w5 = 2*L*p2 + p1
__global__ __launch_bounds__(256) void spmm8_p2(const int* __restrict__ rp,
                                                const int2* __restrict__ meta,
                                                const u16* __restrict__ x,
                                                const u16* __restrict__ z,
                                                u16* __restrict__ y, int n) {
    int r = blockIdx.x * 64 + (threadIdx.x >> 2);
    if (r >= n) return;
    int t = threadIdx.x & 3;
    float acc[8] = {0.f, 0.f, 0.f, 0.f, 0.f, 0.f, 0.f, 0.f};
    spmm8_acc(rp, meta, x, r, t, acc);
    if (t == 0) {
        uint4 zv = *reinterpret_cast<const uint4*>(z + (size_t)r * 8);
        float zz[8] = {bflo(zv.x), bfhi(zv.x), bflo(zv.y), bfhi(zv.y),
                       bflo(zv.z), bfhi(zv.z), bflo(zv.w), bfhi(zv.w)};
        uint4 o;
        o.x = pack2(2.f * acc[0] + zz[0], 2.f * acc[1] + zz[1]);
        o.y = pack2(2.f * acc[2] + zz[2], 2.f * acc[3] + zz[3]);
        o.z = pack2(2.f * acc[4] + zz[4], 2.f * acc[5] + zz[5]);
        o.w = pack2(2.f * acc[6] + zz[6], 2.f * acc[7] + zz[7]);
        *reinterpret_cast<uint4*>(y + (size_t)r * 8) = o;
    }
}

// out = log_softmax(L*w5 + p0 + b4) over 5 classes, fp32 out
__global__ __launch_bounds__(256) void spmm8_lsm(const int* __restrict__ rp,
                                                 const int2* __restrict__ meta,
                                                 const u16* __restrict__ x,
                                                 const u16* __restrict__ z,
                                                 const float* __restrict__ bias,
                                                 float* __restrict__ out, int n) {
    int r = blockIdx.x * 64 + (threadIdx.x >> 2);
    if (r >= n) return;
    int t = threadIdx.x & 3;
    float acc[8] = {0.f, 0.f, 0.f, 0.f, 0.f, 0.f, 0.f, 0.f};
    spmm8_acc(rp, meta, x, r, t, acc);
    if (t == 0) {
        uint4 zv = *reinterpret_cast<const uint4*>(z + (size_t)r * 8);
        float zz[8] = {bflo(zv.x), bfhi(zv.x), bflo(zv.y), bfhi(zv.y),
                       bflo(zv.z), bfhi(zv.z), bflo(zv.w), bfhi(zv.w)};
        float val[5];
#pragma unroll
        for (int j = 0; j < 5; ++j) val[j] = acc[j] + zz[j] + bias[j];
        float mx = val[0];
#pragma unroll
        for (int j = 1; j < 5; ++j) mx = fmaxf(mx, val[j]);
        float s = 0.f;
#pragma unroll
        for (int j = 0; j < 5; ++j) s += expf(val[j] - mx);
        float l = logf(s);
#pragma unroll
        for (int j = 0; j < 5; ++j) out[(size_t)r * 5 + j] = val[j] - mx - l;
    }
}

// ---------------- MFMA GEMMs ----------------

__global__ __launch_bounds__(256) void gemm_u(const u16* __restrict__ A,
                                              const u16* __restrict__ Wp,
                                              u16* __restrict__ u0, u16* __restrict__ u1,
                                              u16* __restrict__ u2, int n) {
    int wave = threadIdx.x >> 6;
    int lane = threadIdx.x & 63;
    int r0 = blockIdx.x * 64 + wave * 16;
    int row = r0 + (lane & 15);
    int rowc = row < n ? row : n - 1;
    int kofs = (lane >> 4) * 8;
    f32x4 acc[12] = {};
    for (int kt = 0; kt < 4; ++kt) {
        bf16x8 a = *reinterpret_cast<const bf16x8*>(A + (size_t)rowc * 128 + kt * 32 + kofs);
        const u16* wb = Wp + (size_t)kt * 12 * 512 + (size_t)lane * 8;
#pragma unroll
        for (int nt = 0; nt < 12; ++nt) {
            bf16x8 b = *reinterpret_cast<const bf16x8*>(wb + nt * 512);
            acc[nt] = __builtin_amdgcn_mfma_f32_16x16x32_bf16(a, b, acc[nt], 0, 0, 0);
        }
    }
    int col = lane & 15;
    u16* U[3] = {u0, u1, u2};
#pragma unroll
    for (int nt = 0; nt < 12; ++nt) {
        u16* dst = U[nt >> 2];
        int cc = (nt & 3) * 16 + col;
#pragma unroll
        for (int i = 0; i < 4; ++i) {
            int rr = r0 + (lane >> 4) * 4 + i;
            if (rr < n) dst[(size_t)rr * 64 + cc] = f2bf(acc[nt][i]);
        }
    }
}

__global__ __launch_bounds__(256) void gemm3_mfma(const u16* __restrict__ A0,
                                                  const u16* __restrict__ A1,
                                                  const u16* __restrict__ A2,
                                                  const u16* __restrict__ Wp,
                                                  const float* __restrict__ bias,
                                                  u16* __restrict__ out, int n) {
    int wave = threadIdx.x >> 6;
    int lane = threadIdx.x & 63;
    int r0 = blockIdx.x * 64 + wave * 16;
    int row = r0 + (lane & 15);
    int rowc = row < n ? row : n - 1;
    int kofs = (lane >> 4) * 8;
    const u16* Ap[3] = {A0, A1, A2};
    f32x4 acc[4] = {};
    for (int kt = 0; kt < 6; ++kt) {
        const u16* Asrc = Ap[kt >> 1];
        int c0 = (kt & 1) * 32;
        bf16x8 a = *reinterpret_cast<const bf16x8*>(Asrc + (size_t)rowc * 64 + c0 + kofs);
        const u16* wb = Wp + (size_t)kt * 4 * 512 + (size_t)lane * 8;
#pragma unroll
        for (int nt = 0; nt < 4; ++nt) {
            bf16x8 b = *reinterpret_cast<const bf16x8*>(wb + nt * 512);
            acc[nt] = __builtin_amdgcn_mfma_f32_16x16x32_bf16(a, b, acc[nt], 0, 0, 0);
        }
    }
    int col = lane & 15;
#pragma unroll
    for (int nt = 0; nt < 4; ++nt) {
        float bb = bias[nt * 16 + col];
#pragma unroll
        for (int i = 0; i < 4; ++i) {
            int rr = r0 + (lane >> 4) * 4 + i;
            if (rr < n) {
                float v = fmaxf(acc[nt][i] + bb, 0.f);
                out[(size_t)rr * 64 + nt * 16 + col] = f2bf(v);
            }
        }
    }
}

__global__ __launch_bounds__(256) void gemm_proj(const u16* __restrict__ A,
                                                 const u16* __restrict__ Wp,
                                                 u16* __restrict__ p0, u16* __restrict__ p1,
                                                 u16* __restrict__ p2, int n) {
    int wave = threadIdx.x >> 6;
    int lane = threadIdx.x & 63;
    int r0 = blockIdx.x * 64 + wave * 16;
    int row = r0 + (lane & 15);
    int rowc = row < n ? row : n - 1;
    int kofs = (lane >> 4) * 8;
    f32x4 acc[2] = {};
    for (int kt = 0; kt < 2; ++kt) {
        bf16x8 a = *reinterpret_cast<const bf16x8*>(A + (size_t)rowc * 64 + kt * 32 + kofs);
        const u16* wb = Wp + (size_t)kt * 2 * 512 + (size_t)lane * 8;
#pragma unroll
        for (int nt = 0; nt < 2; ++nt) {
            bf16x8 b = *reinterpret_cast<const bf16x8*>(wb + nt * 512);
            acc[nt] = __builtin_amdgcn_mfma_f32_16x16x32_bf16(a, b, acc[nt], 0, 0, 0);
        }
    }
    int col = lane & 15;
    u16* P[3] = {p0, p1, p2};
#pragma unroll
    for (int nt = 0; nt < 2; ++nt) {
        int c = nt * 16 + col;
        if (c < 24) {
            u16* dst = P[c >> 3];
            int j = c & 7;
#pragma unroll
            for (int i = 0; i < 4; ++i) {
                int rr = r0 + (lane >> 4) * 4 + i;
                if (rr < n) dst[(size_t)rr * 8 + j] = f2bf(acc[nt][i]);
            }
        }
    }
}

// ---------------- launch ----------------

static inline size_t alignup(size_t v) { return (v + 255) & ~(size_t)255; }

extern "C" void kernel_launch(void* const* d_in, const int* in_sizes, int n_in,
                              void* d_out, int out_size, void* d_ws, size_t ws_size,
                              hipStream_t stream) {
    const float* x  = (const float*)d_in[0];
    const int*   ei = (const int*)d_in[1];
    const float* ew = (const float*)d_in[2];
    const float* W1 = (const float*)d_in[3];
    const float* b1 = (const float*)d_in[4];
    const float* W3 = (const float*)d_in[5];
    const float* b3 = (const float*)d_in[6];
    const float* W4 = (const float*)d_in[7];
    const float* b4 = (const float*)d_in[8];
    float* out = (float*)d_out;

    const int D = 128, H = 64;
    const int N = in_sizes[0] / D;
    const int E = in_sizes[2];
    const int* row = ei;
    const int* col = ei + E;

    char* ws = (char*)d_ws;
    size_t off = 0;
    auto alloc = [&](size_t bytes) { size_t o = off; off += alignup(bytes); return o; };

    float* dinv   = (float*)(ws + alloc((size_t)N * 4));
    int*   rowp   = (int*)  (ws + alloc((size_t)(N + 1) * 4));
    int*   bintot = (int*)  (ws + alloc(MAXSB * 4));
    int*   P      = (int*)  (ws + alloc((size_t)MAXSB * PB * 4));
    int2*  meta   = (int2*) (ws + alloc((size_t)E * 8));
    int2*  rec    = (int2*) (ws + alloc((size_t)E * 8));
    u16*   xb     = (u16*)  (ws + alloc((size_t)N * D * 2));
    u16*   A      = (u16*)  (ws + alloc((size_t)N * H * 2));
    u16*   B      = (u16*)  (ws + alloc((size_t)N * H * 2));
    u16*   C      = (u16*)  (ws + alloc((size_t)N * H * 2));
    u16*   Dd     = (u16*)  (ws + alloc((size_t)N * H * 2));
    u16*   P0     = (u16*)  (ws + alloc((size_t)N * 8 * 2));
    u16*   P1     = (u16*)  (ws + alloc((size_t)N * 8 * 2));
    u16*   P2     = (u16*)  (ws + alloc((size_t)N * 8 * 2));
    u16*   P3     = (u16*)  (ws + alloc((size_t)N * 8 * 2));
    u16*   Wpu    = (u16*)  (ws + alloc((size_t)4 * 12 * 512 * 2));
    u16*   Wp3    = (u16*)  (ws + alloc((size_t)6 * 4 * 512 * 2));
    u16*   Wpp    = (u16*)  (ws + alloc((size_t)2 * 2 * 512 * 2));

    const int NB = (N + SB - 1) / SB;     // super-bins (196 at N=100k)
    const int EB = (E + PB - 1) / PB;     // edges per partition block

    dim3 blk(256);

    // ---- CSR build (no global hot atomics) ----
    binA<<<PB, blk, 0, stream>>>(row, P, E, NB, EB);
    binB1<<<NB, blk, 0, stream>>>(P, bintot);
    binC<<<PB, blk, 0, stream>>>(row, col, ew, P, bintot, rec, E, NB, EB);
    binD1<<<NB, blk, 0, stream>>>(rec, bintot, rowp, dinv, N, NB);
    binD2<<<NB, blk, 0, stream>>>(rec, bintot, rowp, dinv, meta, N, NB);

    // ---- prep (independent of CSR) ----
    int n2 = N * D / 2;
    prep<<<(n2 + 4864 + 255) / 256, blk, 0, stream>>>(x, (unsigned*)xb, n2, W1, W3, W4,
                                                      Wpu, Wp3, Wpp);

    int g64 = (N + 15) / 16;   // 16 rows/block (16 threads/row)
    int gG  = (N + 63) / 64;
    int g8  = (N + 63) / 64;

    // ---- layer 1: u=[u0|u1|u2]=x@Wc ; w=2*L*u2+u1 ; h1=relu(L*w+u0+b1) ----
    gemm_u<<<gG, blk, 0, stream>>>(xb, Wpu, A, B, C, N);                   // u0=A u1=B u2=C
    spmm64<1><<<g64, blk, 0, stream>>>(rowp, meta, C, B, nullptr, Dd, N);  // w -> Dd
    spmm64<3><<<g64, blk, 0, stream>>>(rowp, meta, Dd, A, b1, B, N);       // h1 -> B

    // ---- layer 2: Ty1=L*h1 ; Ty2=2*L*Ty1-h1 ; h2=relu([h1|Ty1|Ty2]@W3+b3) ----
    spmm64<0><<<g64, blk, 0, stream>>>(rowp, meta, B, nullptr, nullptr, C, N);  // Ty1 -> C
    spmm64<2><<<g64, blk, 0, stream>>>(rowp, meta, C, B, nullptr, A, N);        // Ty2 -> A
    gemm3_mfma<<<gG, blk, 0, stream>>>(B, C, A, Wp3, b3, Dd, N);                // h2 -> Dd

    // ---- layer 3: p=[p0|p1|p2]=h2@Wc3 ; w5=2*L*p2+p1 ; out=lsm(L*w5+p0+b4) ----
    gemm_proj<<<gG, blk, 0, stream>>>(Dd, Wpp, P0, P1, P2, N);
    spmm8_p2<<<g8, blk, 0, stream>>>(rowp, meta, P2, P1, P3, N);
    spmm8_lsm<<<g8, blk, 0, stream>>>(rowp, meta, P3, P0, b4, out, N);
}

// Round 13
// 266.707 us; speedup vs baseline: 1.3799x; 1.0695x over previous
//
#include <hip/hip_runtime.h>
#include <cstdint>
#include <cstddef>

typedef unsigned short u16;
typedef __attribute__((ext_vector_type(8))) short bf16x8;
typedef __attribute__((ext_vector_type(4))) float f32x4;

#define PB 1024    // partition blocks for binA/binC
#define MAXSB 256  // max super-bins (N <= 131072 at 512 rows/bin)
#define SB 512     // rows per super-bin
#define CAP 12288  // LDS perm capacity in binD2

// ---------------- bf16 helpers (RNE) ----------------
__device__ __forceinline__ float bflo(unsigned u) { return __uint_as_float(u << 16); }
__device__ __forceinline__ float bfhi(unsigned u) { return __uint_as_float(u & 0xFFFF0000u); }
__device__ __forceinline__ u16 f2bf(float f) {
    unsigned u = __float_as_uint(f);
    u += 0x7FFFu + ((u >> 16) & 1u);
    return (u16)(u >> 16);
}
__device__ __forceinline__ unsigned pack2(float a, float b) {
    return (unsigned)f2bf(a) | ((unsigned)f2bf(b) << 16);
}

// ================= CSR build: super-binned, zero global hot atomics =================
// super-bin = 512 rows (row>>9); record = {col | (row&511)<<17, w}

__global__ __launch_bounds__(256) void binA(const int* __restrict__ row, int* __restrict__ P,
                                            int E, int NB, int EB) {
    __shared__ int hist[MAXSB];
    int b = blockIdx.x;
    hist[threadIdx.x] = 0;
    __syncthreads();
    int e0 = b * EB, e1 = min(E, e0 + EB);
    for (int e = e0 + threadIdx.x; e < e1; e += 256)
        atomicAdd(&hist[row[e] >> 9], 1);
    __syncthreads();
    if (threadIdx.x < NB) P[(size_t)threadIdx.x * PB + b] = hist[threadIdx.x];
}

// per-bin exclusive scan over the PB=1024 block-partials; emit bin totals
__global__ __launch_bounds__(256) void binB1(int* __restrict__ P, int* __restrict__ bintot) {
    __shared__ int sh[256];
    int* p = P + (size_t)blockIdx.x * PB;
    int tid = threadIdx.x;
    int base = tid * 4;
    int v[4];
#pragma unroll
    for (int j = 0; j < 4; ++j) v[j] = p[base + j];
    int s = v[0] + v[1] + v[2] + v[3];
    sh[tid] = s;
    __syncthreads();
    for (int off = 1; off < 256; off <<= 1) {
        int t = (tid >= off) ? sh[tid - off] : 0;
        __syncthreads();
        sh[tid] += t;
        __syncthreads();
    }
    int run = sh[tid] - s;
#pragma unroll
    for (int j = 0; j < 4; ++j) { p[base + j] = run; run += v[j]; }
    if (tid == 255) bintot[blockIdx.x] = sh[255];
}

// helper: inclusive scan of bintot into bs[] (256 entries, in LDS)
__device__ __forceinline__ void bs_scan(int* bs, const int* bintot, int NB, int tid) {
    bs[tid] = (tid < NB) ? bintot[tid] : 0;
    __syncthreads();
    for (int off = 1; off < 256; off <<= 1) {
        int t = (tid >= off) ? bs[tid - off] : 0;
        __syncthreads();
        bs[tid] += t;
        __syncthreads();
    }
}

__global__ __launch_bounds__(256) void binC(const int* __restrict__ row, const int* __restrict__ col,
                                            const float* __restrict__ w, const int* __restrict__ P,
                                            const int* __restrict__ bintot, int2* __restrict__ rec,
                                            int E, int NB, int EB) {
    __shared__ int bs[MAXSB];
    __shared__ int cur[MAXSB];
    int b = blockIdx.x;
    int tid = threadIdx.x;
    bs_scan(bs, bintot, NB, tid);
    if (tid < NB) cur[tid] = (tid ? bs[tid - 1] : 0) + P[(size_t)tid * PB + b];
    __syncthreads();
    int e0 = b * EB, e1 = min(E, e0 + EB);
    for (int e = e0 + tid; e < e1; e += 256) {
        int r = row[e];
        int bin = r >> 9;
        int slot = atomicAdd(&cur[bin], 1);
        rec[slot] = make_int2(col[e] | ((r & 511) << 17), __float_as_int(w[e]));
    }
}

// per-bin counts + deg -> rowp + dinv (wave-level scan, 256 threads)
__global__ __launch_bounds__(256) void binD1(const int2* __restrict__ rec,
                                             const int* __restrict__ bintot,
                                             int* __restrict__ rowp, float* __restrict__ dinv,
                                             int N, int NB) {
    __shared__ int bs[MAXSB];
    __shared__ int cnt[SB];
    __shared__ float deg[SB];
    __shared__ int wsum[4];
    int bin = blockIdx.x;
    int tid = threadIdx.x;
    bs_scan(bs, bintot, NB, tid);
    int e0 = bin ? bs[bin - 1] : 0;
    int e1 = bs[bin];
    cnt[tid] = 0; cnt[tid + 256] = 0;
    deg[tid] = 0.f; deg[tid + 256] = 0.f;
    __syncthreads();
    for (int e = e0 + tid; e < e1; e += 256) {
        int2 v = rec[e];
        int rl = (v.x >> 17) & 511;
        atomicAdd(&cnt[rl], 1);
        atomicAdd(&deg[rl], __int_as_float(v.y));
    }
    __syncthreads();
    int a = cnt[2 * tid], b = cnt[2 * tid + 1];
    int p = a + b;
    int lane = tid & 63, wv = tid >> 6;
    int incl = p;
    for (int off = 1; off < 64; off <<= 1) {
        int t = __shfl_up(incl, off);
        if (lane >= off) incl += t;
    }
    if (lane == 63) wsum[wv] = incl;
    __syncthreads();
    if (tid == 0) {
        int s = 0;
#pragma unroll
        for (int i = 0; i < 4; ++i) { int t = wsum[i]; wsum[i] = s; s += t; }
    }
    __syncthreads();
    int excl = incl - p + wsum[wv];
    int base = bin * SB;
    int rows = min(SB, N - base);
    if (2 * tid < rows) {
        rowp[base + 2 * tid] = e0 + excl;
        float d = deg[2 * tid];
        dinv[base + 2 * tid] = d > 0.f ? rsqrtf(d) : 0.f;
    }
    if (2 * tid + 1 < rows) {
        rowp[base + 2 * tid + 1] = e0 + excl + a;
        float d = deg[2 * tid + 1];
        dinv[base + 2 * tid + 1] = d > 0.f ? rsqrtf(d) : 0.f;
    }
    if (bin == NB - 1 && tid == 0) rowp[N] = e1;
}

// permutation in LDS -> coalesced, pre-scaled meta write
__global__ __launch_bounds__(256) void binD2(const int2* __restrict__ rec,
                                             const int* __restrict__ bintot,
                                             const int* __restrict__ rowp,
                                             const float* __restrict__ dinv,
                                             int2* __restrict__ meta, int N, int NB) {
    __shared__ int bs[MAXSB];
    __shared__ int cur[SB];
    __shared__ int perm[CAP];
    int bin = blockIdx.x;
    int tid = threadIdx.x;
    bs_scan(bs, bintot, NB, tid);
    int e0 = bin ? bs[bin - 1] : 0;
    int e1 = bs[bin];
    int base = bin * SB;
    int rows = min(SB, N - base);
    for (int i = tid; i < rows; i += 256) cur[i] = rowp[base + i];
    __syncthreads();
    for (int e = e0 + tid; e < e1; e += 256) {
        int2 v = rec[e];
        int rl = (v.x >> 17) & 511;
        int slot = atomicAdd(&cur[rl], 1);
        int so = slot - e0;
        if (so < CAP) {
            perm[so] = e - e0;
        } else {
            int c = v.x & 0x1FFFF;
            float ev = -dinv[base + rl] * __int_as_float(v.y) * dinv[c];
            meta[slot] = make_int2(c, __float_as_int(ev));
        }
    }
    __syncthreads();
    int lim = min(e1 - e0, CAP);
    for (int s = tid; s < lim; s += 256) {
        int2 v = rec[e0 + perm[s]];
        int rl = (v.x >> 17) & 511;
        int c = v.x & 0x1FFFF;
        float ev = -dinv[base + rl] * __int_as_float(v.y) * dinv[c];
        meta[e0 + s] = make_int2(c, __float_as_int(ev));
    }
}

// ---------------- prep: W packs only (x is consumed fp32-direct by gemm_u) ----------------
__global__ void prep(const float* __restrict__ W1, const float* __restrict__ W3,
                     const float* __restrict__ W4, u16* __restrict__ Wpu,
                     u16* __restrict__ Wp3, u16* __restrict__ Wpp) {
    int gi = blockIdx.x * blockDim.x + threadIdx.x;
    if (gi < 3072) {
        int idx = gi;
        int lane = idx & 63;
        int nt = (idx >> 6) % 12;
        int kt = idx / 768;
        int krow = kt * 32 + (lane >> 4) * 8;
        int c = nt * 16 + (lane & 15);
        u16 tmp[8];
#pragma unroll
        for (int j = 0; j < 8; ++j) {
            int k = krow + j;
            float v;
            if (c < 64)       v = W1[(size_t)k * 64 + c] - W1[2 * 8192 + (size_t)k * 64 + c];
            else if (c < 128) v = W1[8192 + (size_t)k * 64 + (c - 64)];
            else              v = W1[2 * 8192 + (size_t)k * 64 + (c - 128)];
            tmp[j] = f2bf(v);
        }
        *reinterpret_cast<uint4*>(Wpu + (size_t)idx * 8) = *reinterpret_cast<const uint4*>(tmp);
    } else if (gi < 3072 + 1536) {
        int idx = gi - 3072;
        int lane = idx & 63;
        int nt = (idx >> 6) & 3;
        int kt = idx >> 8;
        int krow = kt * 32 + (lane >> 4) * 8;
        int c = nt * 16 + (lane & 15);
        u16 tmp[8];
#pragma unroll
        for (int j = 0; j < 8; ++j) tmp[j] = f2bf(W3[(size_t)(krow + j) * 64 + c]);
        *reinterpret_cast<uint4*>(Wp3 + (size_t)idx * 8) = *reinterpret_cast<const uint4*>(tmp);
    } else if (gi < 3072 + 1536 + 256) {
        int idx = gi - (3072 + 1536);
        int lane = idx & 63;
        int nt = (idx >> 6) & 1;
        int kt = idx >> 7;
        int krow = kt * 32 + (lane >> 4) * 8;
        int c = nt * 16 + (lane & 15);
        u16 tmp[8];
#pragma unroll
        for (int j = 0; j < 8; ++j) {
            int k = krow + j;
            float v = 0.f;
            if (c < 5)                  v = W4[(size_t)k * 5 + c] - W4[640 + (size_t)k * 5 + c];
            else if (c >= 8 && c < 13)  v = W4[320 + (size_t)k * 5 + (c - 8)];
            else if (c >= 16 && c < 21) v = W4[640 + (size_t)k * 5 + (c - 16)];
            tmp[j] = f2bf(v);
        }
        *reinterpret_cast<uint4*>(Wpp + (size_t)idx * 8) = *reinterpret_cast<const uint4*>(tmp);
    }
}

// ---------------- SpMM (CSR) F=64, 16 threads/row (2 edge-groups x 8 f-threads) ----------------
// MODE 0: y = acc ; 1: y = 2*acc + z ; 2: y = 2*acc - z ; 3: y = relu(acc + z + bias)
template <int MODE>
__global__ __launch_bounds__(256) void spmm64(const int* __restrict__ rp,
                                              const int2* __restrict__ meta,
                                              const u16* __restrict__ x,
                                              const u16* __restrict__ z,
                                              const float* __restrict__ bias,
                                              u16* __restrict__ y, int n) {
    int r = blockIdx.x * 16 + (threadIdx.x >> 4);
    if (r >= n) return;
    int sub = (threadIdx.x >> 3) & 1;   // edge half (lane bit 3)
    int f = (threadIdx.x & 7) * 8;
    int e0 = rp[r], e1 = rp[r + 1];
    float acc[8] = {0.f, 0.f, 0.f, 0.f, 0.f, 0.f, 0.f, 0.f};
    auto fma8 = [&](uint4 xv, float w) {
        acc[0] += w * bflo(xv.x); acc[1] += w * bfhi(xv.x);
        acc[2] += w * bflo(xv.y); acc[3] += w * bfhi(xv.y);
        acc[4] += w * bflo(xv.z); acc[5] += w * bfhi(xv.z);
        acc[6] += w * bflo(xv.w); acc[7] += w * bfhi(xv.w);
    };
    int e = e0 + sub;
    for (; e + 6 < e1; e += 8) {
        int2 m0 = meta[e], m1 = meta[e + 2], m2 = meta[e + 4], m3 = meta[e + 6];
        uint4 v0 = *reinterpret_cast<const uint4*>(x + (size_t)m0.x * 64 + f);
        uint4 v1 = *reinterpret_cast<const uint4*>(x + (size_t)m1.x * 64 + f);
        uint4 v2 = *reinterpret_cast<const uint4*>(x + (size_t)m2.x * 64 + f);
        uint4 v3 = *reinterpret_cast<const uint4*>(x + (size_t)m3.x * 64 + f);
        fma8(v0, __int_as_float(m0.y));
        fma8(v1, __int_as_float(m1.y));
        fma8(v2, __int_as_float(m2.y));
        fma8(v3, __int_as_float(m3.y));
    }
    for (; e < e1; e += 2) {
        int2 m = meta[e];
        uint4 xv = *reinterpret_cast<const uint4*>(x + (size_t)m.x * 64 + f);
        fma8(xv, __int_as_float(m.y));
    }
#pragma unroll
    for (int j = 0; j < 8; ++j) acc[j] += __shfl_xor(acc[j], 8);
    if (sub) return;
    if (MODE == 1 || MODE == 2) {
        uint4 zv = *reinterpret_cast<const uint4*>(z + (size_t)r * 64 + f);
        float zz[8] = {bflo(zv.x), bfhi(zv.x), bflo(zv.y), bfhi(zv.y),
                       bflo(zv.z), bfhi(zv.z), bflo(zv.w), bfhi(zv.w)};
#pragma unroll
        for (int j = 0; j < 8; ++j)
            acc[j] = (MODE == 1) ? 2.f * acc[j] + zz[j] : 2.f * acc[j] - zz[j];
    } else if (MODE == 3) {
        uint4 zv = *reinterpret_cast<const uint4*>(z + (size_t)r * 64 + f);
        float zz[8] = {bflo(zv.x), bfhi(zv.x), bflo(zv.y), bfhi(zv.y),
                       bflo(zv.z), bfhi(zv.z), bflo(zv.w), bfhi(zv.w)};
        float4 bl = *reinterpret_cast<const float4*>(bias + f);
        float4 bh = *reinterpret_cast<const float4*>(bias + f + 4);
        float bb[8] = {bl.x, bl.y, bl.z, bl.w, bh.x, bh.y, bh.z, bh.w};
#pragma unroll
        for (int j = 0; j < 8; ++j) acc[j] = fmaxf(acc[j] + zz[j] + bb[j], 0.f);
    }
    uint4 o;
    o.x = pack2(acc[0], acc[1]);
    o.y = pack2(acc[2], acc[3]);
    o.z = pack2(acc[4], acc[5]);
    o.w = pack2(acc[6], acc[7]);
    *reinterpret_cast<uint4*>(y + (size_t)r * 64 + f) = o;
}

// ---------------- SpMM width-8 (padded 5), 4 threads per row ----------------
__device__ __forceinline__ void spmm8_acc(const int* rp, const int2* meta, const u16* x,
                                          int r, int t, float* acc) {
    int e0 = rp[r], e1 = rp[r + 1];
    auto fma8 = [&](uint4 xv, float w) {
        acc[0] += w * bflo(xv.x); acc[1] += w * bfhi(xv.x);
        acc[2] += w * bflo(xv.y); acc[3] += w * bfhi(xv.y);
        acc[4] += w * bflo(xv.z); acc[5] += w * bfhi(xv.z);
        acc[6] += w * bflo(xv.w); acc[7] += w * bfhi(xv.w);
    };
    int e = e0 + t;
    for (; e + 4 < e1; e += 8) {
        int2 m0 = meta[e], m1 = meta[e + 4];
        uint4 v0 = *reinterpret_cast<const uint4*>(x + (size_t)m0.x * 8);
        uint4 v1 = *reinterpret_cast<const uint4*>(x + (size_t)m1.x * 8);
        fma8(v0, __int_as_float(m0.y));
        fma8(v1, __int_as_float(m1.y));
    }
    for (; e < e1; e += 4) {
        int2 m = meta[e];
        uint4 xv = *reinterpret_cast<const uint4*>(x + (size_t)m.x * 8);
        fma8(xv, __int_as_float(m.y));
    }
#pragma unroll
    for (int j = 0; j < 8; ++j) acc[j] += __shfl_xor(acc[j], 1);
#pragma unroll
    for (int j = 0; j < 8; ++j) acc[j] += __shfl_xor(acc[j], 2);
}

// w5 = 2*L*p2 + p1
__global__ __launch_bounds__(256) void spmm8_p2(const int* __restrict__ rp,
                                                const int2* __restrict__ meta,
                                                const u16* __restrict__ x,
                                                const u16* __restrict__ z,
                                                u16* __restrict__ y, int n) {
    int r = blockIdx.x * 64 + (threadIdx.x >> 2);
    if (r >= n) return;
    int t = threadIdx.x & 3;
    float acc[8] = {0.f, 0.f, 0.f, 0.f, 0.f, 0.f, 0.f, 0.f};
    spmm8_acc(rp, meta, x, r, t, acc);
    if (t == 0) {
        uint4 zv = *reinterpret_cast<const uint4*>(z + (size_t)r * 8);
        float zz[8] = {bflo(zv.x), bfhi(zv.x), bflo(zv.y), bfhi(zv.y),
                       bflo(zv.z), bfhi(zv.z), bflo(zv.w), bfhi(zv.w)};
        uint4 o;
        o.x = pack2(2.f * acc[0] + zz[0], 2.f * acc[1] + zz[1]);
        o.y = pack2(2.f * acc[2] + zz[2], 2.f * acc[3] + zz[3]);
        o.z = pack2(2.f * acc[4] + zz[4], 2.f * acc[5] + zz[5]);
        o.w = pack2(2.f * acc[6] + zz[6], 2.f * acc[7] + zz[7]);
        *reinterpret_cast<uint4*>(y + (size_t)r * 8) = o;
    }
}

// out = log_softmax(L*w5 + p0 + b4) over 5 classes, fp32 out
__global__ __launch_bounds__(256) void spmm8_lsm(const int* __restrict__ rp,
                                                 const int2* __restrict__ meta,
                                                 const u16* __restrict__ x,
                                                 const u16* __restrict__ z,
                                                 const float* __restrict__ bias,
                                                 float* __restrict__ out, int n) {
    int r = blockIdx.x * 64 + (threadIdx.x >> 2);
    if (r >= n) return;
    int t = threadIdx.x & 3;
    float acc[8] = {0.f, 0.f, 0.f, 0.f, 0.f, 0.f, 0.f, 0.f};
    spmm8_acc(rp, meta, x, r, t, acc);
    if (t == 0) {
        uint4 zv = *reinterpret_cast<const uint4*>(z + (size_t)r * 8);
        float zz[8] = {bflo(zv.x), bfhi(zv.x), bflo(zv.y), bfhi(zv.y),
                       bflo(zv.z), bfhi(zv.z), bflo(zv.w), bfhi(zv.w)};
        float val[5];
#pragma unroll
        for (int j = 0; j < 5; ++j) val[j] = acc[j] + zz[j] + bias[j];
        float mx = val[0];
#pragma unroll
        for (int j = 1; j < 5; ++j) mx = fmaxf(mx, val[j]);
        float s = 0.f;
#pragma unroll
        for (int j = 0; j < 5; ++j) s += expf(val[j] - mx);
        float l = logf(s);
#pragma unroll
        for (int j = 0; j < 5; ++j) out[(size_t)r * 5 + j] = val[j] - mx - l;
    }
}

// ---------------- MFMA GEMMs ----------------

// layer 1 projection: [u0|u1|u2] = x(fp32, converted in-register) @ Wc (128 x 192)
__global__ __launch_bounds__(256) void gemm_u(const float* __restrict__ X,
                                              const u16* __restrict__ Wp,
                                              u16* __restrict__ u0, u16* __restrict__ u1,
                                              u16* __restrict__ u2, int n) {
    int wave = threadIdx.x >> 6;
    int lane = threadIdx.x & 63;
    int r0 = blockIdx.x * 64 + wave * 16;
    int row = r0 + (lane & 15);
    int rowc = row < n ? row : n - 1;
    int kofs = (lane >> 4) * 8;
    f32x4 acc[12] = {};
    for (int kt = 0; kt < 4; ++kt) {
        const float* xs = X + (size_t)rowc * 128 + kt * 32 + kofs;
        float4 xa = *reinterpret_cast<const float4*>(xs);
        float4 xb4 = *reinterpret_cast<const float4*>(xs + 4);
        u16 tmp[8] = {f2bf(xa.x), f2bf(xa.y), f2bf(xa.z), f2bf(xa.w),
                      f2bf(xb4.x), f2bf(xb4.y), f2bf(xb4.z), f2bf(xb4.w)};
        bf16x8 a = *reinterpret_cast<const bf16x8*>(tmp);
        const u16* wb = Wp + (size_t)kt * 12 * 512 + (size_t)lane * 8;
#pragma unroll
        for (int nt = 0; nt < 12; ++nt) {
            bf16x8 b = *reinterpret_cast<const bf16x8*>(wb + nt * 512);
            acc[nt] = __builtin_amdgcn_mfma_f32_16x16x32_bf16(a, b, acc[nt], 0, 0, 0);
        }
    }
    int col = lane & 15;
    u16* U[3] = {u0, u1, u2};
#pragma unroll
    for (int nt = 0; nt < 12; ++nt) {
        u16* dst = U[nt >> 2];
        int cc = (nt & 3) * 16 + col;
#pragma unroll
        for (int i = 0; i < 4; ++i) {
            int rr = r0 + (lane >> 4) * 4 + i;
            if (rr < n) dst[(size_t)rr * 64 + cc] = f2bf(acc[nt][i]);
        }
    }
}

// layer 2 + layer 3 projection fused:
// h2 = relu([A0|A1|A2] @ W3 + b3) (kept in LDS tile only);
// [p0|p1|p2] = h2 @ Wc3 (64 x 24)
__global__ __launch_bounds__(256) void gemm3_fused(const u16* __restrict__ A0,
                                                   const u16* __restrict__ A1,
                                                   const u16* __restrict__ A2,
                                                   const u16* __restrict__ Wp,
                                                   const float* __restrict__ bias,
                                                   const u16* __restrict__ Wpp,
                                                   u16* __restrict__ p0, u16* __restrict__ p1,
                                                   u16* __restrict__ p2, int n) {
    __shared__ u16 hl[64][72];   // h2 tile, padded to break bank alignment
    int wave = threadIdx.x >> 6;
    int lane = threadIdx.x & 63;
    int r0 = blockIdx.x * 64 + wave * 16;
    int row = r0 + (lane & 15);
    int rowc = row < n ? row : n - 1;
    int kofs = (lane >> 4) * 8;
    const u16* Ap[3] = {A0, A1, A2};
    f32x4 acc[4] = {};
    for (int kt = 0; kt < 6; ++kt) {
        const u16* Asrc = Ap[kt >> 1];
        int c0 = (kt & 1) * 32;
        bf16x8 a = *reinterpret_cast<const bf16x8*>(Asrc + (size_t)rowc * 64 + c0 + kofs);
        const u16* wb = Wp + (size_t)kt * 4 * 512 + (size_t)lane * 8;
#pragma unroll
        for (int nt = 0; nt < 4; ++nt) {
            bf16x8 b = *reinterpret_cast<const bf16x8*>(wb + nt * 512);
            acc[nt] = __builtin_amdgcn_mfma_f32_16x16x32_bf16(a, b, acc[nt], 0, 0, 0);
        }
    }
    int col = lane & 15;
    // write h2 tile (D-layout) into LDS; each wave owns rows [wave*16, wave*16+16)
#pragma unroll
    for (int nt = 0; nt < 4; ++nt) {
        float bb = bias[nt * 16 + col];
#pragma unroll
        for (int i = 0; i < 4; ++i) {
            float v = fmaxf(acc[nt][i] + bb, 0.f);
            hl[wave * 16 + (lane >> 4) * 4 + i][nt * 16 + col] = f2bf(v);
        }
    }
    __syncthreads();
    // proj: read own rows in A-frag layout, 2 kt x 2 nt MFMAs
    f32x4 acc2[2] = {};
#pragma unroll
    for (int kt = 0; kt < 2; ++kt) {
        bf16x8 a = *reinterpret_cast<const bf16x8*>(&hl[wave * 16 + (lane & 15)][kt * 32 + kofs]);
        const u16* wb = Wpp + (size_t)kt * 2 * 512 + (size_t)lane * 8;
#pragma unroll
        for (int nt = 0; nt < 2; ++nt) {
            bf16x8 b = *reinterpret_cast<const bf16x8*>(wb + nt * 512);
            acc2[nt] = __builtin_amdgcn_mfma_f32_16x16x32_bf16(a, b, acc2[nt], 0, 0, 0);
        }
    }
    u16* P[3] = {p0, p1, p2};
#pragma unroll
    for (int nt = 0; nt < 2; ++nt) {
        int c = nt * 16 + col;
        if (c < 24) {
            u16* dst = P[c >> 3];
            int j = c & 7;
#pragma unroll
            for (int i = 0; i < 4; ++i) {
                int rr = r0 + (lane >> 4) * 4 + i;
                if (rr < n) dst[(size_t)rr * 8 + j] = f2bf(acc2[nt][i]);
            }
        }
    }
}

// ---------------- launch ----------------

static inline size_t alignup(size_t v) { return (v + 255) & ~(size_t)255; }

extern "C" void kernel_launch(void* const* d_in, const int* in_sizes, int n_in,
                              void* d_out, int out_size, void* d_ws, size_t ws_size,
                              hipStream_t stream) {
    const float* x  = (const float*)d_in[0];
    const int*   ei = (const int*)d_in[1];
    const float* ew = (const float*)d_in[2];
    const float* W1 = (const float*)d_in[3];
    const float* b1 = (const float*)d_in[4];
    const float* W3 = (const float*)d_in[5];
    const float* b3 = (const float*)d_in[6];
    const float* W4 = (const float*)d_in[7];
    const float* b4 = (const float*)d_in[8];
    float* out = (float*)d_out;

    const int D = 128, H = 64;
    const int N = in_sizes[0] / D;
    const int E = in_sizes[2];
    const int* row = ei;
    const int* col = ei + E;

    char* ws = (char*)d_ws;
    size_t off = 0;
    auto alloc = [&](size_t bytes) { size_t o = off; off += alignup(bytes); return o; };

    float* dinv   = (float*)(ws + alloc((size_t)N * 4));
    int*   rowp   = (int*)  (ws + alloc((size_t)(N + 1) * 4));
    int*   bintot = (int*)  (ws + alloc(MAXSB * 4));
    int*   P      = (int*)  (ws + alloc((size_t)MAXSB * PB * 4));
    int2*  meta   = (int2*) (ws + alloc((size_t)E * 8));
    int2*  rec    = (int2*) (ws + alloc((size_t)E * 8));
    u16*   A      = (u16*)  (ws + alloc((size_t)N * H * 2));
    u16*   B      = (u16*)  (ws + alloc((size_t)N * H * 2));
    u16*   C      = (u16*)  (ws + alloc((size_t)N * H * 2));
    u16*   Dd     = (u16*)  (ws + alloc((size_t)N * H * 2));
    u16*   P0     = (u16*)  (ws + alloc((size_t)N * 8 * 2));
    u16*   P1     = (u16*)  (ws + alloc((size_t)N * 8 * 2));
    u16*   P2     = (u16*)  (ws + alloc((size_t)N * 8 * 2));
    u16*   P3     = (u16*)  (ws + alloc((size_t)N * 8 * 2));
    u16*   Wpu    = (u16*)  (ws + alloc((size_t)4 * 12 * 512 * 2));
    u16*   Wp3    = (u16*)  (ws + alloc((size_t)6 * 4 * 512 * 2));
    u16*   Wpp    = (u16*)  (ws + alloc((size_t)2 * 2 * 512 * 2));

    const int NB = (N + SB - 1) / SB;     // super-bins (196 at N=100k)
    const int EB = (E + PB - 1) / PB;     // edges per partition block

    dim3 blk(256);

    // ---- CSR build (no global hot atomics) ----
    binA<<<PB, blk, 0, stream>>>(row, P, E, NB, EB);
    binB1<<<NB, blk, 0, stream>>>(P, bintot);
    binC<<<PB, blk, 0, stream>>>(row, col, ew, P, bintot, rec, E, NB, EB);
    binD1<<<NB, blk, 0, stream>>>(rec, bintot, rowp, dinv, N, NB);
    binD2<<<NB, blk, 0, stream>>>(rec, bintot, rowp, dinv, meta, N, NB);

    // ---- prep: weight packs only ----
    prep<<<(4864 + 255) / 256, blk, 0, stream>>>(W1, W3, W4, Wpu, Wp3, Wpp);

    int g64 = (N + 15) / 16;   // 16 rows/block (16 threads/row)
    int gG  = (N + 63) / 64;
    int g8  = (N + 63) / 64;

    // ---- layer 1: u=[u0|u1|u2]=x@Wc ; w=2*L*u2+u1 ; h1=relu(L*w+u0+b1) ----
    gemm_u<<<gG, blk, 0, stream>>>(x, Wpu, A, B, C, N);                    // u0=A u1=B u2=C
    spmm64<1><<<g64, blk, 0, stream>>>(rowp, meta, C, B, nullptr, Dd, N);  // w -> Dd
    spmm64<3><<<g64, blk, 0, stream>>>(rowp, meta, Dd, A, b1, B, N);       // h1 -> B

    // ---- layer 2 + proj: Ty1=L*h1 ; Ty2=2*L*Ty1-h1 ; p=relu([h1|Ty1|Ty2]@W3+b3)@Wc3 ----
    spmm64<0><<<g64, blk, 0, stream>>>(rowp, meta, B, nullptr, nullptr, C, N);  // Ty1 -> C
    spmm64<2><<<g64, blk, 0, stream>>>(rowp, meta, C, B, nullptr, A, N);        // Ty2 -> A
    gemm3_fused<<<gG, blk, 0, stream>>>(B, C, A, Wp3, b3, Wpp, P0, P1, P2, N);

    // ---- layer 3: w5=2*L*p2+p1 ; out=lsm(L*w5+p0+b4) ----
    spmm8_p2<<<g8, blk, 0, stream>>>(rowp, meta, P2, P1, P3, N);
    spmm8_lsm<<<g8, blk, 0, stream>>>(rowp, meta, P3, P0, b4, out, N);
}